// Round 9
// baseline (355.857 us; speedup 1.0000x reference)
//
#include <hip/hip_runtime.h>

#define DIN  128
#define DOUT 64
#define BW   512    // nodes per bucket (power of 2)
#define BSH  9      // log2(BW)
#define EPC  4096   // edges per chunk
#define NSTATB 400  // stat partial blocks

// ---------- K1: per-chunk, per-bucket histograms for BOTH directions ----------
__global__ __launch_bounds__(256) void k_countboth(const int* __restrict__ src,
                                                   const int* __restrict__ dst,
                                                   unsigned* __restrict__ counts,
                                                   int NBUK, int NC, int E) {
    __shared__ int h0[256], h1[256];
    for (int j = threadIdx.x; j < NBUK; j += 256) { h0[j] = 0; h1[j] = 0; }
    __syncthreads();
    int start = blockIdx.x * EPC;
    int end = min(start + EPC, E);
    for (int i = start + threadIdx.x; i < end; i += 256) {
        atomicAdd(&h0[dst[i] >> BSH], 1);
        atomicAdd(&h1[src[i] >> BSH], 1);
    }
    __syncthreads();
    int M = NBUK * NC;
    for (int j = threadIdx.x; j < NBUK; j += 256) {
        counts[j * NC + blockIdx.x]     = (unsigned)h0[j];
        counts[M + j * NC + blockIdx.x] = (unsigned)h1[j];
    }
}

// ---------- generic 3-kernel exclusive scan ----------
__global__ __launch_bounds__(256) void k_scanA(const unsigned* __restrict__ data,
                                               unsigned* __restrict__ bsums, int n) {
    __shared__ unsigned s[256];
    int i = blockIdx.x * 256 + threadIdx.x;
    s[threadIdx.x] = (i < n) ? data[i] : 0u;
    __syncthreads();
    for (int st = 128; st > 0; st >>= 1) {
        if (threadIdx.x < st) s[threadIdx.x] += s[threadIdx.x + st];
        __syncthreads();
    }
    if (threadIdx.x == 0) bsums[blockIdx.x] = s[0];
}

__global__ __launch_bounds__(1024) void k_scan2(unsigned* __restrict__ bsums, int NB) {
    __shared__ unsigned s[1024];
    int tid = threadIdx.x;
    unsigned v = (tid < NB) ? bsums[tid] : 0u;
    s[tid] = v;
    __syncthreads();
    for (int st = 1; st < 1024; st <<= 1) {
        unsigned t = (tid >= st) ? s[tid - st] : 0u;
        __syncthreads();
        s[tid] += t;
        __syncthreads();
    }
    if (tid < NB) bsums[tid] = s[tid] - v;   // exclusive
}

__global__ __launch_bounds__(256) void k_scanC(unsigned* __restrict__ data,
                                               const unsigned* __restrict__ bsums, int n) {
    __shared__ unsigned s[256];
    int i = blockIdx.x * 256 + threadIdx.x;
    unsigned v = (i < n) ? data[i] : 0u;
    s[threadIdx.x] = v;
    __syncthreads();
    for (int st = 1; st < 256; st <<= 1) {
        unsigned t = (threadIdx.x >= st) ? s[threadIdx.x - st] : 0u;
        __syncthreads();
        s[threadIdx.x] += t;
        __syncthreads();
    }
    if (i < n) data[i] = s[threadIdx.x] - v + bsums[blockIdx.x];
}

// ---------- K5: bucket-major reorder (coalesced block-private segments) ----------
__global__ __launch_bounds__(256) void k_bucket(const int* __restrict__ key,
                                                const int* __restrict__ other,
                                                const unsigned* __restrict__ counts,
                                                int dirOff, unsigned dirBase,
                                                int2* __restrict__ bucketed,
                                                int NBUK, int NC, int E) {
    __shared__ int cur[256];
    for (int j = threadIdx.x; j < NBUK; j += 256)
        cur[j] = (int)(counts[dirOff + j * NC + blockIdx.x] - dirBase);
    __syncthreads();
    int start = blockIdx.x * EPC;
    int end = min(start + EPC, E);
    for (int i = start + threadIdx.x; i < end; i += 256) {
        int k = key[i], o = other[i];
        int pos = atomicAdd(&cur[k >> BSH], 1);
        bucketed[pos] = make_int2(k, o);
    }
}

// ---------- K6: per-bucket CSR finalize — degrees, offsets, private scatter ----------
__global__ __launch_bounds__(256) void k_csr(const int2* __restrict__ bucketed,
                                             const unsigned* __restrict__ counts,
                                             unsigned* __restrict__ off,
                                             int* __restrict__ pay,
                                             unsigned* __restrict__ cnt,
                                             float* __restrict__ dinv,
                                             int dirOff, unsigned dirBase,
                                             int NBUK, int NC, int N, int E) {
    __shared__ int sH[BW];
    __shared__ int sS[2][BW];
    __shared__ int sC[BW];
    int b = blockIdx.x;
    int base = (int)(counts[dirOff + b * NC] - dirBase);
    int end  = (b + 1 < NBUK) ? (int)(counts[dirOff + (b + 1) * NC] - dirBase) : E;

    for (int j = threadIdx.x; j < BW; j += 256) sH[j] = 0;
    __syncthreads();
    for (int i = base + threadIdx.x; i < end; i += 256)
        atomicAdd(&sH[bucketed[i].x & (BW - 1)], 1);
    __syncthreads();
    for (int j = threadIdx.x; j < BW; j += 256) sS[0][j] = sH[j];
    __syncthreads();
    int pin = 0;
    for (int st = 1; st < BW; st <<= 1) {
        for (int j = threadIdx.x; j < BW; j += 256) {
            int v = sS[pin][j];
            if (j >= st) v += sS[pin][j - st];
            sS[pin ^ 1][j] = v;
        }
        __syncthreads();
        pin ^= 1;
    }
    int lo = b * BW;
    for (int j = threadIdx.x; j < BW; j += 256) {
        int excl = j ? sS[pin][j - 1] : 0;
        sC[j] = excl;
        int n = lo + j;
        if (n < N) {
            off[n] = (unsigned)(base + excl);
            if (cnt) {
                cnt[n] = (unsigned)sH[j];
                dinv[n] = rsqrtf((float)sH[j] + 1.f);
            }
        }
    }
    if (threadIdx.x == 0 && b == NBUK - 1) off[N] = (unsigned)E;
    __syncthreads();
    for (int i = base + threadIdx.x; i < end; i += 256) {
        int2 p = bucketed[i];
        int pos = base + atomicAdd(&sC[p.x & (BW - 1)], 1);
        pay[pos] = p.y;
    }
}

// ---------- K7: h0s = dinv[n] * (x[n] @ W) ----------
// R9: LANE = ROW. The R2-R8 invariant (VALUBusy ~20-25%) traced to the
// outer-product mapping's BROADCAST x loads: 64 B moved per wave-instr
// (16 lanes share an address). Transposed assignment fixes it structurally:
// - lane r owns output row base+r: x row loaded per-lane (distinct data,
//   full-width loads, 8 independent per 32-k chunk -> natural MLP).
// - W index depends only on (uniform) loop vars -> compiler scalarizes to
//   s_load on the SCALAR pipe (parallel to VALU); W = 32 KB, K$/L2-hot.
//   (R3 inverted: bulk operand -> vmem per-lane, small reused -> scalar.)
// acc[64]+xa[8] ~ 110 VGPR, zero LDS, zero barriers, 64-thr blocks.
__global__ __launch_bounds__(64) void k_gemm(const float* __restrict__ x,
                                             const float* __restrict__ W,
                                             const float* __restrict__ dinv,
                                             float* __restrict__ h0s, int N) {
    int row = blockIdx.x * 64 + threadIdx.x;
    int rc = min(row, N - 1);                 // clamp for loads; store guarded
    const float* xr = x + (size_t)rc * DIN;

    float acc[DOUT];
#pragma unroll
    for (int c = 0; c < DOUT; ++c) acc[c] = 0.f;

#pragma unroll
    for (int kc = 0; kc < DIN; kc += 32) {
        float4 xa[8];
#pragma unroll
        for (int j = 0; j < 8; ++j)
            xa[j] = *(const float4*)(xr + kc + 4 * j);
#pragma unroll
        for (int j = 0; j < 8; ++j) {
            const float* Wb = W + (size_t)(kc + 4 * j) * DOUT;  // uniform -> s_load
            float4 a = xa[j];
#pragma unroll
            for (int c4 = 0; c4 < 16; ++c4) {
                float4 w0 = *(const float4*)(Wb + 0 * DOUT + 4 * c4);
                float4 w1 = *(const float4*)(Wb + 1 * DOUT + 4 * c4);
                float4 w2 = *(const float4*)(Wb + 2 * DOUT + 4 * c4);
                float4 w3 = *(const float4*)(Wb + 3 * DOUT + 4 * c4);
                acc[4 * c4 + 0] = fmaf(a.x, w0.x, fmaf(a.y, w1.x, fmaf(a.z, w2.x, fmaf(a.w, w3.x, acc[4 * c4 + 0]))));
                acc[4 * c4 + 1] = fmaf(a.x, w0.y, fmaf(a.y, w1.y, fmaf(a.z, w2.y, fmaf(a.w, w3.y, acc[4 * c4 + 1]))));
                acc[4 * c4 + 2] = fmaf(a.x, w0.z, fmaf(a.y, w1.z, fmaf(a.z, w2.z, fmaf(a.w, w3.z, acc[4 * c4 + 2]))));
                acc[4 * c4 + 3] = fmaf(a.x, w0.w, fmaf(a.y, w1.w, fmaf(a.z, w2.w, fmaf(a.w, w3.w, acc[4 * c4 + 3]))));
            }
        }
    }

    if (row < N) {
        float dv = dinv[row];
        float* o = h0s + (size_t)row * DOUT;
#pragma unroll
        for (int c4 = 0; c4 < 16; ++c4) {
            float4 v = make_float4(acc[4 * c4 + 0] * dv, acc[4 * c4 + 1] * dv,
                                   acc[4 * c4 + 2] * dv, acc[4 * c4 + 3] * dv);
            *(float4*)(o + 4 * c4) = v;
        }
    }
}

// ---------- K8: gather agg + fused combine ----------
// One node per 16-lane GROUP. Lane q preloads pay[beg+q]; edge ids come from
// __shfl registers. 8-row unroll -> 8 rows (2KB) in flight per group.
__global__ __launch_bounds__(256) void k_agg(const unsigned* __restrict__ off,
                                             const int* __restrict__ pay,
                                             const float* __restrict__ dinv,
                                             const float* __restrict__ h0s,
                                             const float* __restrict__ b,
                                             float* __restrict__ h, int N) {
    int t = threadIdx.x;
    int grp = t >> 4;          // 0..15
    int q = t & 15;
    int n = blockIdx.x * 16 + grp;
    if (n >= N) return;
    unsigned beg = off[n], end = off[n + 1];
    float4 acc = make_float4(0.f, 0.f, 0.f, 0.f);
    for (unsigned base2 = beg; base2 < end; base2 += 16) {
        unsigned idx = base2 + q;
        int pd = (idx < end) ? pay[idx] : 0;
        int jmax = (int)min(16u, end - base2);
        int j = 0;
        for (; j + 8 <= jmax; j += 8) {
            int s0 = __shfl(pd, j + 0, 16);
            int s1 = __shfl(pd, j + 1, 16);
            int s2 = __shfl(pd, j + 2, 16);
            int s3 = __shfl(pd, j + 3, 16);
            int s4 = __shfl(pd, j + 4, 16);
            int s5 = __shfl(pd, j + 5, 16);
            int s6 = __shfl(pd, j + 6, 16);
            int s7 = __shfl(pd, j + 7, 16);
            float4 a0 = *(const float4*)(h0s + (size_t)s0 * DOUT + 4 * q);
            float4 a1 = *(const float4*)(h0s + (size_t)s1 * DOUT + 4 * q);
            float4 a2 = *(const float4*)(h0s + (size_t)s2 * DOUT + 4 * q);
            float4 a3 = *(const float4*)(h0s + (size_t)s3 * DOUT + 4 * q);
            float4 a4 = *(const float4*)(h0s + (size_t)s4 * DOUT + 4 * q);
            float4 a5 = *(const float4*)(h0s + (size_t)s5 * DOUT + 4 * q);
            float4 a6 = *(const float4*)(h0s + (size_t)s6 * DOUT + 4 * q);
            float4 a7 = *(const float4*)(h0s + (size_t)s7 * DOUT + 4 * q);
            acc.x += ((a0.x + a1.x) + (a2.x + a3.x)) + ((a4.x + a5.x) + (a6.x + a7.x));
            acc.y += ((a0.y + a1.y) + (a2.y + a3.y)) + ((a4.y + a5.y) + (a6.y + a7.y));
            acc.z += ((a0.z + a1.z) + (a2.z + a3.z)) + ((a4.z + a5.z) + (a6.z + a7.z));
            acc.w += ((a0.w + a1.w) + (a2.w + a3.w)) + ((a4.w + a5.w) + (a6.w + a7.w));
        }
        for (; j + 4 <= jmax; j += 4) {
            int s0 = __shfl(pd, j + 0, 16);
            int s1 = __shfl(pd, j + 1, 16);
            int s2 = __shfl(pd, j + 2, 16);
            int s3 = __shfl(pd, j + 3, 16);
            float4 a0 = *(const float4*)(h0s + (size_t)s0 * DOUT + 4 * q);
            float4 a1 = *(const float4*)(h0s + (size_t)s1 * DOUT + 4 * q);
            float4 a2 = *(const float4*)(h0s + (size_t)s2 * DOUT + 4 * q);
            float4 a3 = *(const float4*)(h0s + (size_t)s3 * DOUT + 4 * q);
            acc.x += (a0.x + a1.x) + (a2.x + a3.x);
            acc.y += (a0.y + a1.y) + (a2.y + a3.y);
            acc.z += (a0.z + a1.z) + (a2.z + a3.z);
            acc.w += (a0.w + a1.w) + (a2.w + a3.w);
        }
        for (; j < jmax; ++j) {
            int s = __shfl(pd, j, 16);
            float4 a = *(const float4*)(h0s + (size_t)s * DOUT + 4 * q);
            acc.x += a.x; acc.y += a.y; acc.z += a.z; acc.w += a.w;
        }
    }
    float dv = dinv[n];
    float4 hs = *(const float4*)(h0s + (size_t)n * DOUT + 4 * q);
    float4 bv = *(const float4*)(b + 4 * q);
    float4 o;
    o.x = dv * (acc.x + hs.x) + bv.x;
    o.y = dv * (acc.y + hs.y) + bv.y;
    o.z = dv * (acc.z + hs.z) + bv.z;
    o.w = dv * (acc.w + hs.w) + bv.w;
    *(float4*)(h + (size_t)n * DOUT + 4 * q) = o;
}

// ---------- K9: gather energy + S (same group-per-node structure, 8-unroll) ----------
__global__ __launch_bounds__(256) void k_energy(const unsigned* __restrict__ off,
                                                const int* __restrict__ pay,
                                                const float* __restrict__ h,
                                                float* __restrict__ e,
                                                float* __restrict__ S, int N) {
    int t = threadIdx.x;
    int grp = t >> 4;
    int q = t & 15;
    int n = blockIdx.x * 16 + grp;
    if (n >= N) return;
    unsigned beg = off[n], end = off[n + 1];
    float4 hm = *(const float4*)(h + (size_t)n * DOUT + 4 * q);
    float4 Sa = make_float4(0.f, 0.f, 0.f, 0.f);
    float esum = 0.f;
#define EACC(a)                                                                \
    {                                                                          \
        Sa.x += a.x; Sa.y += a.y; Sa.z += a.z; Sa.w += a.w;                    \
        float dx = hm.x - a.x, dy = hm.y - a.y, dz = hm.z - a.z, dw = hm.w - a.w; \
        esum += dx * dx + dy * dy + dz * dz + dw * dw;                         \
    }
    for (unsigned base2 = beg; base2 < end; base2 += 16) {
        unsigned idx = base2 + q;
        int pd = (idx < end) ? pay[idx] : 0;
        int jmax = (int)min(16u, end - base2);
        int j = 0;
        for (; j + 8 <= jmax; j += 8) {
            int s0 = __shfl(pd, j + 0, 16);
            int s1 = __shfl(pd, j + 1, 16);
            int s2 = __shfl(pd, j + 2, 16);
            int s3 = __shfl(pd, j + 3, 16);
            int s4 = __shfl(pd, j + 4, 16);
            int s5 = __shfl(pd, j + 5, 16);
            int s6 = __shfl(pd, j + 6, 16);
            int s7 = __shfl(pd, j + 7, 16);
            float4 a0 = *(const float4*)(h + (size_t)s0 * DOUT + 4 * q);
            float4 a1 = *(const float4*)(h + (size_t)s1 * DOUT + 4 * q);
            float4 a2 = *(const float4*)(h + (size_t)s2 * DOUT + 4 * q);
            float4 a3 = *(const float4*)(h + (size_t)s3 * DOUT + 4 * q);
            float4 a4 = *(const float4*)(h + (size_t)s4 * DOUT + 4 * q);
            float4 a5 = *(const float4*)(h + (size_t)s5 * DOUT + 4 * q);
            float4 a6 = *(const float4*)(h + (size_t)s6 * DOUT + 4 * q);
            float4 a7 = *(const float4*)(h + (size_t)s7 * DOUT + 4 * q);
            EACC(a0) EACC(a1) EACC(a2) EACC(a3) EACC(a4) EACC(a5) EACC(a6) EACC(a7)
        }
        for (; j + 4 <= jmax; j += 4) {
            int s0 = __shfl(pd, j + 0, 16);
            int s1 = __shfl(pd, j + 1, 16);
            int s2 = __shfl(pd, j + 2, 16);
            int s3 = __shfl(pd, j + 3, 16);
            float4 a0 = *(const float4*)(h + (size_t)s0 * DOUT + 4 * q);
            float4 a1 = *(const float4*)(h + (size_t)s1 * DOUT + 4 * q);
            float4 a2 = *(const float4*)(h + (size_t)s2 * DOUT + 4 * q);
            float4 a3 = *(const float4*)(h + (size_t)s3 * DOUT + 4 * q);
            EACC(a0) EACC(a1) EACC(a2) EACC(a3)
        }
        for (; j < jmax; ++j) {
            int s = __shfl(pd, j, 16);
            float4 a = *(const float4*)(h + (size_t)s * DOUT + 4 * q);
            EACC(a)
        }
    }
#undef EACC
#pragma unroll
    for (int m = 1; m <= 8; m <<= 1) esum += __shfl_xor(esum, m, 16);
    if (q == 0) e[n] = esum;
    *(float4*)(S + (size_t)n * DOUT + 4 * q) = Sa;
}

// ---------- K10: per-block softmax partials (m, Z, M) ----------
__global__ __launch_bounds__(256) void k_stats1(const float* __restrict__ e,
                                                const float* __restrict__ Tptr,
                                                float* __restrict__ part, int N) {
    float T = *Tptr;
    float m = -3.4e38f;
    int i0 = blockIdx.x * 256 + threadIdx.x;
    int stride = gridDim.x * 256;
    for (int i = i0; i < N; i += stride) m = fmaxf(m, -e[i] / T);
    __shared__ float sm[256];
    sm[threadIdx.x] = m;
    __syncthreads();
    for (int s = 128; s > 0; s >>= 1) {
        if (threadIdx.x < s) sm[threadIdx.x] = fmaxf(sm[threadIdx.x], sm[threadIdx.x + s]);
        __syncthreads();
    }
    float bm = sm[0];
    __syncthreads();
    float z = 0.f, mm = 0.f;
    for (int i = i0; i < N; i += stride) {
        float t = -e[i] / T - bm;
        float w = __expf(t);
        z += w;
        mm += w * t;
    }
    __shared__ float sz[256], sM[256];
    sz[threadIdx.x] = z;
    sM[threadIdx.x] = mm;
    __syncthreads();
    for (int s = 128; s > 0; s >>= 1) {
        if (threadIdx.x < s) {
            sz[threadIdx.x] += sz[threadIdx.x + s];
            sM[threadIdx.x] += sM[threadIdx.x + s];
        }
        __syncthreads();
    }
    if (threadIdx.x == 0) {
        part[blockIdx.x * 3 + 0] = bm;
        part[blockIdx.x * 3 + 1] = sz[0];
        part[blockIdx.x * 3 + 2] = sM[0];
    }
}

// ---------- K11: merge partials -> st = {m, Z, M} ----------
__global__ __launch_bounds__(256) void k_stats2(const float* __restrict__ part,
                                                float* __restrict__ st, int P) {
    __shared__ float sm[256];
    float m = -3.4e38f;
    for (int i = threadIdx.x; i < P; i += 256) m = fmaxf(m, part[3 * i]);
    sm[threadIdx.x] = m;
    __syncthreads();
    for (int s = 128; s > 0; s >>= 1) {
        if (threadIdx.x < s) sm[threadIdx.x] = fmaxf(sm[threadIdx.x], sm[threadIdx.x + s]);
        __syncthreads();
    }
    float gm = sm[0];
    __syncthreads();
    float Z = 0.f, M = 0.f;
    for (int i = threadIdx.x; i < P; i += 256) {
        float mb = part[3 * i], zb = part[3 * i + 1], Mb = part[3 * i + 2];
        float d = mb - gm, eb = __expf(d);
        Z += eb * zb;
        M += eb * (Mb + d * zb);
    }
    __shared__ float sz[256], sM2[256];
    sz[threadIdx.x] = Z;
    sM2[threadIdx.x] = M;
    __syncthreads();
    for (int s = 128; s > 0; s >>= 1) {
        if (threadIdx.x < s) {
            sz[threadIdx.x] += sz[threadIdx.x + s];
            sM2[threadIdx.x] += sM2[threadIdx.x + s];
        }
        __syncthreads();
    }
    if (threadIdx.x == 0) {
        st[0] = gm;
        st[1] = sz[0];
        st[2] = sM2[0];
    }
}

// ---------- K12: c_n = p_n * (logp_n + H) ----------
__global__ __launch_bounds__(256) void k_coef(const float* __restrict__ e,
                                              const float* __restrict__ Tptr,
                                              const float* __restrict__ st,
                                              float* __restrict__ c, int N) {
    int n = blockIdx.x * 256 + threadIdx.x;
    if (n >= N) return;
    float T = *Tptr;
    float gm = st[0], Z = st[1], M = st[2];
    float logZ = logf(Z);
    float H = logZ - M / Z;
    float t = -e[n] / T - gm;
    float lp = t - logZ;
    c[n] = expf(lp) * (lp + H);
}

// ---------- K13: out-CSR gather of A,B + fused final (8-unroll) ----------
__global__ __launch_bounds__(256) void k_grad_final(const unsigned* __restrict__ off,
                                                    const int* __restrict__ pay,
                                                    const float* __restrict__ c,
                                                    const float* __restrict__ h,
                                                    const float* __restrict__ S,
                                                    const unsigned* __restrict__ cnt,
                                                    const float* __restrict__ wptr,
                                                    float* __restrict__ out, int N) {
    int t = threadIdx.x;
    int grp = t >> 4;
    int q = t & 15;
    int n = blockIdx.x * 16 + grp;
    if (n >= N) return;
    unsigned beg = off[n], end = off[n + 1];
    float A = 0.f;
    float4 B = make_float4(0.f, 0.f, 0.f, 0.f);
    for (unsigned base2 = beg; base2 < end; base2 += 16) {
        unsigned idx = base2 + q;
        int pd = 0;
        float cv = 0.f;
        if (idx < end) {
            pd = pay[idx];
            cv = c[pd];
        }
        int jmax = (int)min(16u, end - base2);
        int j = 0;
        for (; j + 8 <= jmax; j += 8) {
            int s0 = __shfl(pd, j + 0, 16);
            int s1 = __shfl(pd, j + 1, 16);
            int s2 = __shfl(pd, j + 2, 16);
            int s3 = __shfl(pd, j + 3, 16);
            int s4 = __shfl(pd, j + 4, 16);
            int s5 = __shfl(pd, j + 5, 16);
            int s6 = __shfl(pd, j + 6, 16);
            int s7 = __shfl(pd, j + 7, 16);
            float c0 = __shfl(cv, j + 0, 16);
            float c1 = __shfl(cv, j + 1, 16);
            float c2 = __shfl(cv, j + 2, 16);
            float c3 = __shfl(cv, j + 3, 16);
            float c4 = __shfl(cv, j + 4, 16);
            float c5 = __shfl(cv, j + 5, 16);
            float c6 = __shfl(cv, j + 6, 16);
            float c7 = __shfl(cv, j + 7, 16);
            float4 a0 = *(const float4*)(h + (size_t)s0 * DOUT + 4 * q);
            float4 a1 = *(const float4*)(h + (size_t)s1 * DOUT + 4 * q);
            float4 a2 = *(const float4*)(h + (size_t)s2 * DOUT + 4 * q);
            float4 a3 = *(const float4*)(h + (size_t)s3 * DOUT + 4 * q);
            float4 a4 = *(const float4*)(h + (size_t)s4 * DOUT + 4 * q);
            float4 a5 = *(const float4*)(h + (size_t)s5 * DOUT + 4 * q);
            float4 a6 = *(const float4*)(h + (size_t)s6 * DOUT + 4 * q);
            float4 a7 = *(const float4*)(h + (size_t)s7 * DOUT + 4 * q);
            A += ((c0 + c1) + (c2 + c3)) + ((c4 + c5) + (c6 + c7));
            B.x = fmaf(c0, a0.x, fmaf(c1, a1.x, fmaf(c2, a2.x, fmaf(c3, a3.x, B.x))));
            B.x = fmaf(c4, a4.x, fmaf(c5, a5.x, fmaf(c6, a6.x, fmaf(c7, a7.x, B.x))));
            B.y = fmaf(c0, a0.y, fmaf(c1, a1.y, fmaf(c2, a2.y, fmaf(c3, a3.y, B.y))));
            B.y = fmaf(c4, a4.y, fmaf(c5, a5.y, fmaf(c6, a6.y, fmaf(c7, a7.y, B.y))));
            B.z = fmaf(c0, a0.z, fmaf(c1, a1.z, fmaf(c2, a2.z, fmaf(c3, a3.z, B.z))));
            B.z = fmaf(c4, a4.z, fmaf(c5, a5.z, fmaf(c6, a6.z, fmaf(c7, a7.z, B.z))));
            B.w = fmaf(c0, a0.w, fmaf(c1, a1.w, fmaf(c2, a2.w, fmaf(c3, a3.w, B.w))));
            B.w = fmaf(c4, a4.w, fmaf(c5, a5.w, fmaf(c6, a6.w, fmaf(c7, a7.w, B.w))));
        }
        for (; j + 4 <= jmax; j += 4) {
            int s0 = __shfl(pd, j + 0, 16);
            int s1 = __shfl(pd, j + 1, 16);
            int s2 = __shfl(pd, j + 2, 16);
            int s3 = __shfl(pd, j + 3, 16);
            float c0 = __shfl(cv, j + 0, 16);
            float c1 = __shfl(cv, j + 1, 16);
            float c2 = __shfl(cv, j + 2, 16);
            float c3 = __shfl(cv, j + 3, 16);
            float4 a0 = *(const float4*)(h + (size_t)s0 * DOUT + 4 * q);
            float4 a1 = *(const float4*)(h + (size_t)s1 * DOUT + 4 * q);
            float4 a2 = *(const float4*)(h + (size_t)s2 * DOUT + 4 * q);
            float4 a3 = *(const float4*)(h + (size_t)s3 * DOUT + 4 * q);
            A += (c0 + c1) + (c2 + c3);
            B.x = fmaf(c0, a0.x, fmaf(c1, a1.x, fmaf(c2, a2.x, fmaf(c3, a3.x, B.x))));
            B.y = fmaf(c0, a0.y, fmaf(c1, a1.y, fmaf(c2, a2.y, fmaf(c3, a3.y, B.y))));
            B.z = fmaf(c0, a0.z, fmaf(c1, a1.z, fmaf(c2, a2.z, fmaf(c3, a3.z, B.z))));
            B.w = fmaf(c0, a0.w, fmaf(c1, a1.w, fmaf(c2, a2.w, fmaf(c3, a3.w, B.w))));
        }
        for (; j < jmax; ++j) {
            int s = __shfl(pd, j, 16);
            float cj = __shfl(cv, j, 16);
            float4 a = *(const float4*)(h + (size_t)s * DOUT + 4 * q);
            A += cj;
            B.x = fmaf(cj, a.x, B.x);
            B.y = fmaf(cj, a.y, B.y);
            B.z = fmaf(cj, a.z, B.z);
            B.w = fmaf(cj, a.w, B.w);
        }
    }
    size_t idx4 = (size_t)n * DOUT + 4 * q;
    float4 hm = *(const float4*)(h + idx4);
    float4 Sv = *(const float4*)(S + idx4);
    float cn = c[n];
    float cc = (float)cnt[n];
    float w = *wptr;
    float4 o;
    o.x = hm.x + w * (2.f * cn * (cc * hm.x - Sv.x) + 2.f * (A * hm.x - B.x));
    o.y = hm.y + w * (2.f * cn * (cc * hm.y - Sv.y) + 2.f * (A * hm.y - B.y));
    o.z = hm.z + w * (2.f * cn * (cc * hm.z - Sv.z) + 2.f * (A * hm.z - B.z));
    o.w = hm.w + w * (2.f * cn * (cc * hm.w - Sv.w) + 2.f * (A * hm.w - B.w));
    *(float4*)(out + idx4) = o;
}

extern "C" void kernel_launch(void* const* d_in, const int* in_sizes, int n_in,
                              void* d_out, int out_size, void* d_ws, size_t ws_size,
                              hipStream_t stream) {
    const float* x    = (const float*)d_in[0];
    const int*   ei   = (const int*)d_in[1];
    const float* wptr = (const float*)d_in[2];
    const float* Tptr = (const float*)d_in[3];
    const float* W    = (const float*)d_in[4];
    const float* b    = (const float*)d_in[5];
    float* out = (float*)d_out;

    const int N  = in_sizes[0] / DIN;   // 100000
    const int E  = in_sizes[1] / 2;     // 1000000
    const int NE = N * DOUT;
    const int* src = ei;
    const int* dst = ei + E;

    const int NBUK = (N + BW - 1) / BW;         // 196
    const int NC   = (E + EPC - 1) / EPC;       // 245
    const int M    = NBUK * NC;
    const int M2   = 2 * M;
    const int NBs  = (M2 + 255) / 256;          // <= 1024

    // workspace layout
    float*    h0s  = (float*)d_ws;                    // NE (reused as S later)
    float*    h    = h0s + NE;                        // NE
    int2*     bkt  = (int2*)(h + NE);                 // E int2 (8 MB, reused per dir)
    int*      pay1 = (int*)(bkt + E);                 // E (in-CSR payload: src ids)
    int*      pay2 = pay1 + E;                        // E (out-CSR payload: dst ids)
    unsigned* counts = (unsigned*)(pay2 + E);         // 2*M
    unsigned* bsum = counts + M2;                     // <=1024
    unsigned* off1 = bsum + 1024;                     // N+1
    unsigned* off2 = off1 + N + 1;                    // N+1
    unsigned* cnt  = off2 + N + 1;                    // N
    float*    e    = (float*)(cnt + N);               // N
    float*    c    = e + N;                           // N
    float*    dinv = c + N;                           // N
    float*    part = dinv + N;                        // 3*NSTATB
    float*    st   = part + 3 * NSTATB;               // 3
    float*    S    = h0s;                             // reuse after k_agg

    const int nodeG = (N + 15) / 16;    // 16 nodes per 256-thread block
    const int nodeBlocks = (N + 255) / 256;

    // build both direction counts + one combined scan
    k_countboth<<<NC, 256, 0, stream>>>(src, dst, counts, NBUK, NC, E);
    k_scanA<<<NBs, 256, 0, stream>>>(counts, bsum, M2);
    k_scan2<<<1, 1024, 0, stream>>>(bsum, NBs);
    k_scanC<<<NBs, 256, 0, stream>>>(counts, bsum, M2);

    // direction 0: in-CSR (key=dst, payload=src) -> off1/pay1 + cnt/dinv
    k_bucket<<<NC, 256, 0, stream>>>(dst, src, counts, 0, 0u, bkt, NBUK, NC, E);
    k_csr<<<NBUK, 256, 0, stream>>>(bkt, counts, off1, pay1, cnt, dinv,
                                    0, 0u, NBUK, NC, N, E);
    // direction 1: out-CSR (key=src, payload=dst) -> off2/pay2
    k_bucket<<<NC, 256, 0, stream>>>(src, dst, counts, M, (unsigned)E, bkt, NBUK, NC, E);
    k_csr<<<NBUK, 256, 0, stream>>>(bkt, counts, off2, pay2, nullptr, nullptr,
                                    M, (unsigned)E, NBUK, NC, N, E);

    k_gemm<<<(N + 63) / 64, 64, 0, stream>>>(x, W, dinv, h0s, N);
    k_agg<<<nodeG, 256, 0, stream>>>(off1, pay1, dinv, h0s, b, h, N);
    k_energy<<<nodeG, 256, 0, stream>>>(off1, pay1, h, e, S, N);
    k_stats1<<<NSTATB, 256, 0, stream>>>(e, Tptr, part, N);
    k_stats2<<<1, 256, 0, stream>>>(part, st, NSTATB);
    k_coef<<<nodeBlocks, 256, 0, stream>>>(e, Tptr, st, c, N);
    k_grad_final<<<nodeG, 256, 0, stream>>>(off2, pay2, c, h, S, cnt, wptr, out, N);
}

// Round 10
// 319.516 us; speedup vs baseline: 1.1137x; 1.1137x over previous
//
#include <hip/hip_runtime.h>

#define DIN  128
#define DOUT 64
#define BW   512    // nodes per bucket (power of 2)
#define BSH  9      // log2(BW)
#define EPC  4096   // edges per chunk
#define NSTATB 400  // stat partial blocks

typedef short short8v __attribute__((ext_vector_type(8)));   // 8 bf16 (4 VGPRs)
typedef float f32x4 __attribute__((ext_vector_type(4)));

// ---------- K1: per-chunk, per-bucket histograms for BOTH directions ----------
__global__ __launch_bounds__(256) void k_countboth(const int* __restrict__ src,
                                                   const int* __restrict__ dst,
                                                   unsigned* __restrict__ counts,
                                                   int NBUK, int NC, int E) {
    __shared__ int h0[256], h1[256];
    for (int j = threadIdx.x; j < NBUK; j += 256) { h0[j] = 0; h1[j] = 0; }
    __syncthreads();
    int start = blockIdx.x * EPC;
    int end = min(start + EPC, E);
    for (int i = start + threadIdx.x; i < end; i += 256) {
        atomicAdd(&h0[dst[i] >> BSH], 1);
        atomicAdd(&h1[src[i] >> BSH], 1);
    }
    __syncthreads();
    int M = NBUK * NC;
    for (int j = threadIdx.x; j < NBUK; j += 256) {
        counts[j * NC + blockIdx.x]     = (unsigned)h0[j];
        counts[M + j * NC + blockIdx.x] = (unsigned)h1[j];
    }
}

// ---------- generic 3-kernel exclusive scan ----------
__global__ __launch_bounds__(256) void k_scanA(const unsigned* __restrict__ data,
                                               unsigned* __restrict__ bsums, int n) {
    __shared__ unsigned s[256];
    int i = blockIdx.x * 256 + threadIdx.x;
    s[threadIdx.x] = (i < n) ? data[i] : 0u;
    __syncthreads();
    for (int st = 128; st > 0; st >>= 1) {
        if (threadIdx.x < st) s[threadIdx.x] += s[threadIdx.x + st];
        __syncthreads();
    }
    if (threadIdx.x == 0) bsums[blockIdx.x] = s[0];
}

__global__ __launch_bounds__(1024) void k_scan2(unsigned* __restrict__ bsums, int NB) {
    __shared__ unsigned s[1024];
    int tid = threadIdx.x;
    unsigned v = (tid < NB) ? bsums[tid] : 0u;
    s[tid] = v;
    __syncthreads();
    for (int st = 1; st < 1024; st <<= 1) {
        unsigned t = (tid >= st) ? s[tid - st] : 0u;
        __syncthreads();
        s[tid] += t;
        __syncthreads();
    }
    if (tid < NB) bsums[tid] = s[tid] - v;   // exclusive
}

__global__ __launch_bounds__(256) void k_scanC(unsigned* __restrict__ data,
                                               const unsigned* __restrict__ bsums, int n) {
    __shared__ unsigned s[256];
    int i = blockIdx.x * 256 + threadIdx.x;
    unsigned v = (i < n) ? data[i] : 0u;
    s[threadIdx.x] = v;
    __syncthreads();
    for (int st = 1; st < 256; st <<= 1) {
        unsigned t = (threadIdx.x >= st) ? s[threadIdx.x - st] : 0u;
        __syncthreads();
        s[threadIdx.x] += t;
        __syncthreads();
    }
    if (i < n) data[i] = s[threadIdx.x] - v + bsums[blockIdx.x];
}

// ---------- K5: bucket-major reorder (coalesced block-private segments) ----------
__global__ __launch_bounds__(256) void k_bucket(const int* __restrict__ key,
                                                const int* __restrict__ other,
                                                const unsigned* __restrict__ counts,
                                                int dirOff, unsigned dirBase,
                                                int2* __restrict__ bucketed,
                                                int NBUK, int NC, int E) {
    __shared__ int cur[256];
    for (int j = threadIdx.x; j < NBUK; j += 256)
        cur[j] = (int)(counts[dirOff + j * NC + blockIdx.x] - dirBase);
    __syncthreads();
    int start = blockIdx.x * EPC;
    int end = min(start + EPC, E);
    for (int i = start + threadIdx.x; i < end; i += 256) {
        int k = key[i], o = other[i];
        int pos = atomicAdd(&cur[k >> BSH], 1);
        bucketed[pos] = make_int2(k, o);
    }
}

// ---------- K6: per-bucket CSR finalize — degrees, offsets, private scatter ----------
__global__ __launch_bounds__(256) void k_csr(const int2* __restrict__ bucketed,
                                             const unsigned* __restrict__ counts,
                                             unsigned* __restrict__ off,
                                             int* __restrict__ pay,
                                             unsigned* __restrict__ cnt,
                                             float* __restrict__ dinv,
                                             int dirOff, unsigned dirBase,
                                             int NBUK, int NC, int N, int E) {
    __shared__ int sH[BW];
    __shared__ int sS[2][BW];
    __shared__ int sC[BW];
    int b = blockIdx.x;
    int base = (int)(counts[dirOff + b * NC] - dirBase);
    int end  = (b + 1 < NBUK) ? (int)(counts[dirOff + (b + 1) * NC] - dirBase) : E;

    for (int j = threadIdx.x; j < BW; j += 256) sH[j] = 0;
    __syncthreads();
    for (int i = base + threadIdx.x; i < end; i += 256)
        atomicAdd(&sH[bucketed[i].x & (BW - 1)], 1);
    __syncthreads();
    for (int j = threadIdx.x; j < BW; j += 256) sS[0][j] = sH[j];
    __syncthreads();
    int pin = 0;
    for (int st = 1; st < BW; st <<= 1) {
        for (int j = threadIdx.x; j < BW; j += 256) {
            int v = sS[pin][j];
            if (j >= st) v += sS[pin][j - st];
            sS[pin ^ 1][j] = v;
        }
        __syncthreads();
        pin ^= 1;
    }
    int lo = b * BW;
    for (int j = threadIdx.x; j < BW; j += 256) {
        int excl = j ? sS[pin][j - 1] : 0;
        sC[j] = excl;
        int n = lo + j;
        if (n < N) {
            off[n] = (unsigned)(base + excl);
            if (cnt) {
                cnt[n] = (unsigned)sH[j];
                dinv[n] = rsqrtf((float)sH[j] + 1.f);
            }
        }
    }
    if (threadIdx.x == 0 && b == NBUK - 1) off[N] = (unsigned)E;
    __syncthreads();
    for (int i = base + threadIdx.x; i < end; i += 256) {
        int2 p = bucketed[i];
        int pos = base + atomicAdd(&sC[p.x & (BW - 1)], 1);
        pay[pos] = p.y;
    }
}

// ---------- bf16 split helpers ----------
__device__ __forceinline__ void split_bf16(float f, short& hi, short& lo) {
    unsigned u = __float_as_uint(f);
    hi = (short)(u >> 16);                              // truncate -> bf16 hi
    float hf = __uint_as_float(u & 0xFFFF0000u);
    float lf = f - hf;                                  // exact residual
    unsigned ul = __float_as_uint(lf);
    ul = ul + 0x7FFFu + ((ul >> 16) & 1u);              // RNE
    lo = (short)(ul >> 16);
}

// ---------- K7a: pack W into MFMA B-fragments (hi/lo), lane-linear ----------
// Slot convention (consistent for A and B, so any bijection is valid):
// lane l (l&15 = col-in-tile, g=l>>4), element i  <->  k = kst*32 + 8*g + i.
// frag index = (kst*4 + nt)*64 + l. Two 16 KB buffers; L2-hot for all blocks.
__global__ __launch_bounds__(256) void k_prepw(const float* __restrict__ W,
                                               short8v* __restrict__ whf,
                                               short8v* __restrict__ wlf) {
    for (int idx = threadIdx.x; idx < 16 * 64; idx += 256) {
        int l = idx & 63;
        int ntkst = idx >> 6;          // = kst*4 + nt
        int kst = ntkst >> 2;
        int nt = ntkst & 3;
        int g = l >> 4;
        int c = nt * 16 + (l & 15);
        short8v hs, ls;
#pragma unroll
        for (int i = 0; i < 8; ++i) {
            float f = W[(size_t)(kst * 32 + g * 8 + i) * DOUT + c];
            short hi, lo;
            split_bf16(f, hi, lo);
            hs[i] = hi;
            ls[i] = lo;
        }
        whf[idx] = hs;
        wlf[idx] = ls;
    }
}

// ---------- K7: h0s = dinv[n] * (x[n] @ W)  via split-bf16 MFMA ----------
// R10: after 8 rounds the FP32-VALU path is pinned at ~50us (5x its 10.4us
// floor) with MfmaUtil=0. Switch to the matrix core: 3-term bf16 split
// (xh*wh + xl*wh + xh*wl; dropped xl*wl ~1.5e-5 rel << tolerance).
// Zero LDS, zero barriers: A-fragments read per-lane from global (row=l&15,
// 32B contiguous) and converted in-reg; B-fragments pre-packed by k_prepw,
// loaded lane-linear (fully coalesced, L2-hot). C/D layout per m89 (verified):
// col = lane&15, row = (lane>>4)*4 + reg.
__global__ __launch_bounds__(256) void k_gemm(const float* __restrict__ x,
                                              const short8v* __restrict__ whf,
                                              const short8v* __restrict__ wlf,
                                              const float* __restrict__ dinv,
                                              float* __restrict__ h0s, int N) {
    int l = threadIdx.x & 63;
    int w = threadIdx.x >> 6;              // wave 0..3
    int r0 = blockIdx.x * 64 + w * 16;     // wave's 16-row tile
    int g = l >> 4;
    int arow = r0 + (l & 15);
    int arc = min(arow, N - 1);
    const float* xr = x + (size_t)arc * DIN + g * 8;

    f32x4 acc0 = {0.f, 0.f, 0.f, 0.f};
    f32x4 acc1 = {0.f, 0.f, 0.f, 0.f};
    f32x4 acc2 = {0.f, 0.f, 0.f, 0.f};
    f32x4 acc3 = {0.f, 0.f, 0.f, 0.f};

#pragma unroll
    for (int kst = 0; kst < 4; ++kst) {
        float4 a0 = *(const float4*)(xr + kst * 32);
        float4 a1 = *(const float4*)(xr + kst * 32 + 4);
        short8v ah, al;
        {
            short hi, lo;
            split_bf16(a0.x, hi, lo); ah[0] = hi; al[0] = lo;
            split_bf16(a0.y, hi, lo); ah[1] = hi; al[1] = lo;
            split_bf16(a0.z, hi, lo); ah[2] = hi; al[2] = lo;
            split_bf16(a0.w, hi, lo); ah[3] = hi; al[3] = lo;
            split_bf16(a1.x, hi, lo); ah[4] = hi; al[4] = lo;
            split_bf16(a1.y, hi, lo); ah[5] = hi; al[5] = lo;
            split_bf16(a1.z, hi, lo); ah[6] = hi; al[6] = lo;
            split_bf16(a1.w, hi, lo); ah[7] = hi; al[7] = lo;
        }
        int fb = kst * 4 * 64 + l;
        short8v bh0 = whf[fb + 0 * 64];
        short8v bl0 = wlf[fb + 0 * 64];
        short8v bh1 = whf[fb + 1 * 64];
        short8v bl1 = wlf[fb + 1 * 64];
        short8v bh2 = whf[fb + 2 * 64];
        short8v bl2 = wlf[fb + 2 * 64];
        short8v bh3 = whf[fb + 3 * 64];
        short8v bl3 = wlf[fb + 3 * 64];
        acc0 = __builtin_amdgcn_mfma_f32_16x16x32_bf16(ah, bh0, acc0, 0, 0, 0);
        acc0 = __builtin_amdgcn_mfma_f32_16x16x32_bf16(al, bh0, acc0, 0, 0, 0);
        acc0 = __builtin_amdgcn_mfma_f32_16x16x32_bf16(ah, bl0, acc0, 0, 0, 0);
        acc1 = __builtin_amdgcn_mfma_f32_16x16x32_bf16(ah, bh1, acc1, 0, 0, 0);
        acc1 = __builtin_amdgcn_mfma_f32_16x16x32_bf16(al, bh1, acc1, 0, 0, 0);
        acc1 = __builtin_amdgcn_mfma_f32_16x16x32_bf16(ah, bl1, acc1, 0, 0, 0);
        acc2 = __builtin_amdgcn_mfma_f32_16x16x32_bf16(ah, bh2, acc2, 0, 0, 0);
        acc2 = __builtin_amdgcn_mfma_f32_16x16x32_bf16(al, bh2, acc2, 0, 0, 0);
        acc2 = __builtin_amdgcn_mfma_f32_16x16x32_bf16(ah, bl2, acc2, 0, 0, 0);
        acc3 = __builtin_amdgcn_mfma_f32_16x16x32_bf16(ah, bh3, acc3, 0, 0, 0);
        acc3 = __builtin_amdgcn_mfma_f32_16x16x32_bf16(al, bh3, acc3, 0, 0, 0);
        acc3 = __builtin_amdgcn_mfma_f32_16x16x32_bf16(ah, bl3, acc3, 0, 0, 0);
    }

    // C/D: col = l&15, row = g*4 + i  (m89-verified)
    int cbase = l & 15;
#pragma unroll
    for (int i = 0; i < 4; ++i) {
        int n = r0 + g * 4 + i;
        if (n < N) {
            float dv = dinv[n];
            float* o = h0s + (size_t)n * DOUT + cbase;
            o[0]  = acc0[i] * dv;
            o[16] = acc1[i] * dv;
            o[32] = acc2[i] * dv;
            o[48] = acc3[i] * dv;
        }
    }
}

// ---------- K8: gather agg + fused combine ----------
__global__ __launch_bounds__(256) void k_agg(const unsigned* __restrict__ off,
                                             const int* __restrict__ pay,
                                             const float* __restrict__ dinv,
                                             const float* __restrict__ h0s,
                                             const float* __restrict__ b,
                                             float* __restrict__ h, int N) {
    int t = threadIdx.x;
    int grp = t >> 4;          // 0..15
    int q = t & 15;
    int n = blockIdx.x * 16 + grp;
    if (n >= N) return;
    unsigned beg = off[n], end = off[n + 1];
    float4 acc = make_float4(0.f, 0.f, 0.f, 0.f);
    for (unsigned base2 = beg; base2 < end; base2 += 16) {
        unsigned idx = base2 + q;
        int pd = (idx < end) ? pay[idx] : 0;
        int jmax = (int)min(16u, end - base2);
        int j = 0;
        for (; j + 8 <= jmax; j += 8) {
            int s0 = __shfl(pd, j + 0, 16);
            int s1 = __shfl(pd, j + 1, 16);
            int s2 = __shfl(pd, j + 2, 16);
            int s3 = __shfl(pd, j + 3, 16);
            int s4 = __shfl(pd, j + 4, 16);
            int s5 = __shfl(pd, j + 5, 16);
            int s6 = __shfl(pd, j + 6, 16);
            int s7 = __shfl(pd, j + 7, 16);
            float4 a0 = *(const float4*)(h0s + (size_t)s0 * DOUT + 4 * q);
            float4 a1 = *(const float4*)(h0s + (size_t)s1 * DOUT + 4 * q);
            float4 a2 = *(const float4*)(h0s + (size_t)s2 * DOUT + 4 * q);
            float4 a3 = *(const float4*)(h0s + (size_t)s3 * DOUT + 4 * q);
            float4 a4 = *(const float4*)(h0s + (size_t)s4 * DOUT + 4 * q);
            float4 a5 = *(const float4*)(h0s + (size_t)s5 * DOUT + 4 * q);
            float4 a6 = *(const float4*)(h0s + (size_t)s6 * DOUT + 4 * q);
            float4 a7 = *(const float4*)(h0s + (size_t)s7 * DOUT + 4 * q);
            acc.x += ((a0.x + a1.x) + (a2.x + a3.x)) + ((a4.x + a5.x) + (a6.x + a7.x));
            acc.y += ((a0.y + a1.y) + (a2.y + a3.y)) + ((a4.y + a5.y) + (a6.y + a7.y));
            acc.z += ((a0.z + a1.z) + (a2.z + a3.z)) + ((a4.z + a5.z) + (a6.z + a7.z));
            acc.w += ((a0.w + a1.w) + (a2.w + a3.w)) + ((a4.w + a5.w) + (a6.w + a7.w));
        }
        for (; j + 4 <= jmax; j += 4) {
            int s0 = __shfl(pd, j + 0, 16);
            int s1 = __shfl(pd, j + 1, 16);
            int s2 = __shfl(pd, j + 2, 16);
            int s3 = __shfl(pd, j + 3, 16);
            float4 a0 = *(const float4*)(h0s + (size_t)s0 * DOUT + 4 * q);
            float4 a1 = *(const float4*)(h0s + (size_t)s1 * DOUT + 4 * q);
            float4 a2 = *(const float4*)(h0s + (size_t)s2 * DOUT + 4 * q);
            float4 a3 = *(const float4*)(h0s + (size_t)s3 * DOUT + 4 * q);
            acc.x += (a0.x + a1.x) + (a2.x + a3.x);
            acc.y += (a0.y + a1.y) + (a2.y + a3.y);
            acc.z += (a0.z + a1.z) + (a2.z + a3.z);
            acc.w += (a0.w + a1.w) + (a2.w + a3.w);
        }
        for (; j < jmax; ++j) {
            int s = __shfl(pd, j, 16);
            float4 a = *(const float4*)(h0s + (size_t)s * DOUT + 4 * q);
            acc.x += a.x; acc.y += a.y; acc.z += a.z; acc.w += a.w;
        }
    }
    float dv = dinv[n];
    float4 hs = *(const float4*)(h0s + (size_t)n * DOUT + 4 * q);
    float4 bv = *(const float4*)(b + 4 * q);
    float4 o;
    o.x = dv * (acc.x + hs.x) + bv.x;
    o.y = dv * (acc.y + hs.y) + bv.y;
    o.z = dv * (acc.z + hs.z) + bv.z;
    o.w = dv * (acc.w + hs.w) + bv.w;
    *(float4*)(h + (size_t)n * DOUT + 4 * q) = o;
}

// ---------- K9: gather energy + S ----------
__global__ __launch_bounds__(256) void k_energy(const unsigned* __restrict__ off,
                                                const int* __restrict__ pay,
                                                const float* __restrict__ h,
                                                float* __restrict__ e,
                                                float* __restrict__ S, int N) {
    int t = threadIdx.x;
    int grp = t >> 4;
    int q = t & 15;
    int n = blockIdx.x * 16 + grp;
    if (n >= N) return;
    unsigned beg = off[n], end = off[n + 1];
    float4 hm = *(const float4*)(h + (size_t)n * DOUT + 4 * q);
    float4 Sa = make_float4(0.f, 0.f, 0.f, 0.f);
    float esum = 0.f;
#define EACC(a)                                                                \
    {                                                                          \
        Sa.x += a.x; Sa.y += a.y; Sa.z += a.z; Sa.w += a.w;                    \
        float dx = hm.x - a.x, dy = hm.y - a.y, dz = hm.z - a.z, dw = hm.w - a.w; \
        esum += dx * dx + dy * dy + dz * dz + dw * dw;                         \
    }
    for (unsigned base2 = beg; base2 < end; base2 += 16) {
        unsigned idx = base2 + q;
        int pd = (idx < end) ? pay[idx] : 0;
        int jmax = (int)min(16u, end - base2);
        int j = 0;
        for (; j + 8 <= jmax; j += 8) {
            int s0 = __shfl(pd, j + 0, 16);
            int s1 = __shfl(pd, j + 1, 16);
            int s2 = __shfl(pd, j + 2, 16);
            int s3 = __shfl(pd, j + 3, 16);
            int s4 = __shfl(pd, j + 4, 16);
            int s5 = __shfl(pd, j + 5, 16);
            int s6 = __shfl(pd, j + 6, 16);
            int s7 = __shfl(pd, j + 7, 16);
            float4 a0 = *(const float4*)(h + (size_t)s0 * DOUT + 4 * q);
            float4 a1 = *(const float4*)(h + (size_t)s1 * DOUT + 4 * q);
            float4 a2 = *(const float4*)(h + (size_t)s2 * DOUT + 4 * q);
            float4 a3 = *(const float4*)(h + (size_t)s3 * DOUT + 4 * q);
            float4 a4 = *(const float4*)(h + (size_t)s4 * DOUT + 4 * q);
            float4 a5 = *(const float4*)(h + (size_t)s5 * DOUT + 4 * q);
            float4 a6 = *(const float4*)(h + (size_t)s6 * DOUT + 4 * q);
            float4 a7 = *(const float4*)(h + (size_t)s7 * DOUT + 4 * q);
            EACC(a0) EACC(a1) EACC(a2) EACC(a3) EACC(a4) EACC(a5) EACC(a6) EACC(a7)
        }
        for (; j + 4 <= jmax; j += 4) {
            int s0 = __shfl(pd, j + 0, 16);
            int s1 = __shfl(pd, j + 1, 16);
            int s2 = __shfl(pd, j + 2, 16);
            int s3 = __shfl(pd, j + 3, 16);
            float4 a0 = *(const float4*)(h + (size_t)s0 * DOUT + 4 * q);
            float4 a1 = *(const float4*)(h + (size_t)s1 * DOUT + 4 * q);
            float4 a2 = *(const float4*)(h + (size_t)s2 * DOUT + 4 * q);
            float4 a3 = *(const float4*)(h + (size_t)s3 * DOUT + 4 * q);
            EACC(a0) EACC(a1) EACC(a2) EACC(a3)
        }
        for (; j < jmax; ++j) {
            int s = __shfl(pd, j, 16);
            float4 a = *(const float4*)(h + (size_t)s * DOUT + 4 * q);
            EACC(a)
        }
    }
#undef EACC
#pragma unroll
    for (int m = 1; m <= 8; m <<= 1) esum += __shfl_xor(esum, m, 16);
    if (q == 0) e[n] = esum;
    *(float4*)(S + (size_t)n * DOUT + 4 * q) = Sa;
}

// ---------- K10: per-block softmax partials (m, Z, M) ----------
__global__ __launch_bounds__(256) void k_stats1(const float* __restrict__ e,
                                                const float* __restrict__ Tptr,
                                                float* __restrict__ part, int N) {
    float T = *Tptr;
    float m = -3.4e38f;
    int i0 = blockIdx.x * 256 + threadIdx.x;
    int stride = gridDim.x * 256;
    for (int i = i0; i < N; i += stride) m = fmaxf(m, -e[i] / T);
    __shared__ float sm[256];
    sm[threadIdx.x] = m;
    __syncthreads();
    for (int s = 128; s > 0; s >>= 1) {
        if (threadIdx.x < s) sm[threadIdx.x] = fmaxf(sm[threadIdx.x], sm[threadIdx.x + s]);
        __syncthreads();
    }
    float bm = sm[0];
    __syncthreads();
    float z = 0.f, mm = 0.f;
    for (int i = i0; i < N; i += stride) {
        float t = -e[i] / T - bm;
        float w = __expf(t);
        z += w;
        mm += w * t;
    }
    __shared__ float sz[256], sM[256];
    sz[threadIdx.x] = z;
    sM[threadIdx.x] = mm;
    __syncthreads();
    for (int s = 128; s > 0; s >>= 1) {
        if (threadIdx.x < s) {
            sz[threadIdx.x] += sz[threadIdx.x + s];
            sM[threadIdx.x] += sM[threadIdx.x + s];
        }
        __syncthreads();
    }
    if (threadIdx.x == 0) {
        part[blockIdx.x * 3 + 0] = bm;
        part[blockIdx.x * 3 + 1] = sz[0];
        part[blockIdx.x * 3 + 2] = sM[0];
    }
}

// ---------- K11: merge partials -> st = {m, Z, M} ----------
__global__ __launch_bounds__(256) void k_stats2(const float* __restrict__ part,
                                                float* __restrict__ st, int P) {
    __shared__ float sm[256];
    float m = -3.4e38f;
    for (int i = threadIdx.x; i < P; i += 256) m = fmaxf(m, part[3 * i]);
    sm[threadIdx.x] = m;
    __syncthreads();
    for (int s = 128; s > 0; s >>= 1) {
        if (threadIdx.x < s) sm[threadIdx.x] = fmaxf(sm[threadIdx.x], sm[threadIdx.x + s]);
        __syncthreads();
    }
    float gm = sm[0];
    __syncthreads();
    float Z = 0.f, M = 0.f;
    for (int i = threadIdx.x; i < P; i += 256) {
        float mb = part[3 * i], zb = part[3 * i + 1], Mb = part[3 * i + 2];
        float d = mb - gm, eb = __expf(d);
        Z += eb * zb;
        M += eb * (Mb + d * zb);
    }
    __shared__ float sz[256], sM2[256];
    sz[threadIdx.x] = Z;
    sM2[threadIdx.x] = M;
    __syncthreads();
    for (int s = 128; s > 0; s >>= 1) {
        if (threadIdx.x < s) {
            sz[threadIdx.x] += sz[threadIdx.x + s];
            sM2[threadIdx.x] += sM2[threadIdx.x + s];
        }
        __syncthreads();
    }
    if (threadIdx.x == 0) {
        st[0] = gm;
        st[1] = sz[0];
        st[2] = sM2[0];
    }
}

// ---------- K12: c_n = p_n * (logp_n + H) ----------
__global__ __launch_bounds__(256) void k_coef(const float* __restrict__ e,
                                              const float* __restrict__ Tptr,
                                              const float* __restrict__ st,
                                              float* __restrict__ c, int N) {
    int n = blockIdx.x * 256 + threadIdx.x;
    if (n >= N) return;
    float T = *Tptr;
    float gm = st[0], Z = st[1], M = st[2];
    float logZ = logf(Z);
    float H = logZ - M / Z;
    float t = -e[n] / T - gm;
    float lp = t - logZ;
    c[n] = expf(lp) * (lp + H);
}

// ---------- K13: out-CSR gather of A,B + fused final (8-unroll) ----------
__global__ __launch_bounds__(256) void k_grad_final(const unsigned* __restrict__ off,
                                                    const int* __restrict__ pay,
                                                    const float* __restrict__ c,
                                                    const float* __restrict__ h,
                                                    const float* __restrict__ S,
                                                    const unsigned* __restrict__ cnt,
                                                    const float* __restrict__ wptr,
                                                    float* __restrict__ out, int N) {
    int t = threadIdx.x;
    int grp = t >> 4;
    int q = t & 15;
    int n = blockIdx.x * 16 + grp;
    if (n >= N) return;
    unsigned beg = off[n], end = off[n + 1];
    float A = 0.f;
    float4 B = make_float4(0.f, 0.f, 0.f, 0.f);
    for (unsigned base2 = beg; base2 < end; base2 += 16) {
        unsigned idx = base2 + q;
        int pd = 0;
        float cv = 0.f;
        if (idx < end) {
            pd = pay[idx];
            cv = c[pd];
        }
        int jmax = (int)min(16u, end - base2);
        int j = 0;
        for (; j + 8 <= jmax; j += 8) {
            int s0 = __shfl(pd, j + 0, 16);
            int s1 = __shfl(pd, j + 1, 16);
            int s2 = __shfl(pd, j + 2, 16);
            int s3 = __shfl(pd, j + 3, 16);
            int s4 = __shfl(pd, j + 4, 16);
            int s5 = __shfl(pd, j + 5, 16);
            int s6 = __shfl(pd, j + 6, 16);
            int s7 = __shfl(pd, j + 7, 16);
            float c0 = __shfl(cv, j + 0, 16);
            float c1 = __shfl(cv, j + 1, 16);
            float c2 = __shfl(cv, j + 2, 16);
            float c3 = __shfl(cv, j + 3, 16);
            float c4 = __shfl(cv, j + 4, 16);
            float c5 = __shfl(cv, j + 5, 16);
            float c6 = __shfl(cv, j + 6, 16);
            float c7 = __shfl(cv, j + 7, 16);
            float4 a0 = *(const float4*)(h + (size_t)s0 * DOUT + 4 * q);
            float4 a1 = *(const float4*)(h + (size_t)s1 * DOUT + 4 * q);
            float4 a2 = *(const float4*)(h + (size_t)s2 * DOUT + 4 * q);
            float4 a3 = *(const float4*)(h + (size_t)s3 * DOUT + 4 * q);
            float4 a4 = *(const float4*)(h + (size_t)s4 * DOUT + 4 * q);
            float4 a5 = *(const float4*)(h + (size_t)s5 * DOUT + 4 * q);
            float4 a6 = *(const float4*)(h + (size_t)s6 * DOUT + 4 * q);
            float4 a7 = *(const float4*)(h + (size_t)s7 * DOUT + 4 * q);
            A += ((c0 + c1) + (c2 + c3)) + ((c4 + c5) + (c6 + c7));
            B.x = fmaf(c0, a0.x, fmaf(c1, a1.x, fmaf(c2, a2.x, fmaf(c3, a3.x, B.x))));
            B.x = fmaf(c4, a4.x, fmaf(c5, a5.x, fmaf(c6, a6.x, fmaf(c7, a7.x, B.x))));
            B.y = fmaf(c0, a0.y, fmaf(c1, a1.y, fmaf(c2, a2.y, fmaf(c3, a3.y, B.y))));
            B.y = fmaf(c4, a4.y, fmaf(c5, a5.y, fmaf(c6, a6.y, fmaf(c7, a7.y, B.y))));
            B.z = fmaf(c0, a0.z, fmaf(c1, a1.z, fmaf(c2, a2.z, fmaf(c3, a3.z, B.z))));
            B.z = fmaf(c4, a4.z, fmaf(c5, a5.z, fmaf(c6, a6.z, fmaf(c7, a7.z, B.z))));
            B.w = fmaf(c0, a0.w, fmaf(c1, a1.w, fmaf(c2, a2.w, fmaf(c3, a3.w, B.w))));
            B.w = fmaf(c4, a4.w, fmaf(c5, a5.w, fmaf(c6, a6.w, fmaf(c7, a7.w, B.w))));
        }
        for (; j + 4 <= jmax; j += 4) {
            int s0 = __shfl(pd, j + 0, 16);
            int s1 = __shfl(pd, j + 1, 16);
            int s2 = __shfl(pd, j + 2, 16);
            int s3 = __shfl(pd, j + 3, 16);
            float c0 = __shfl(cv, j + 0, 16);
            float c1 = __shfl(cv, j + 1, 16);
            float c2 = __shfl(cv, j + 2, 16);
            float c3 = __shfl(cv, j + 3, 16);
            float4 a0 = *(const float4*)(h + (size_t)s0 * DOUT + 4 * q);
            float4 a1 = *(const float4*)(h + (size_t)s1 * DOUT + 4 * q);
            float4 a2 = *(const float4*)(h + (size_t)s2 * DOUT + 4 * q);
            float4 a3 = *(const float4*)(h + (size_t)s3 * DOUT + 4 * q);
            A += (c0 + c1) + (c2 + c3);
            B.x = fmaf(c0, a0.x, fmaf(c1, a1.x, fmaf(c2, a2.x, fmaf(c3, a3.x, B.x))));
            B.y = fmaf(c0, a0.y, fmaf(c1, a1.y, fmaf(c2, a2.y, fmaf(c3, a3.y, B.y))));
            B.z = fmaf(c0, a0.z, fmaf(c1, a1.z, fmaf(c2, a2.z, fmaf(c3, a3.z, B.z))));
            B.w = fmaf(c0, a0.w, fmaf(c1, a1.w, fmaf(c2, a2.w, fmaf(c3, a3.w, B.w))));
        }
        for (; j < jmax; ++j) {
            int s = __shfl(pd, j, 16);
            float cj = __shfl(cv, j, 16);
            float4 a = *(const float4*)(h + (size_t)s * DOUT + 4 * q);
            A += cj;
            B.x = fmaf(cj, a.x, B.x);
            B.y = fmaf(cj, a.y, B.y);
            B.z = fmaf(cj, a.z, B.z);
            B.w = fmaf(cj, a.w, B.w);
        }
    }
    size_t idx4 = (size_t)n * DOUT + 4 * q;
    float4 hm = *(const float4*)(h + idx4);
    float4 Sv = *(const float4*)(S + idx4);
    float cn = c[n];
    float cc = (float)cnt[n];
    float w = *wptr;
    float4 o;
    o.x = hm.x + w * (2.f * cn * (cc * hm.x - Sv.x) + 2.f * (A * hm.x - B.x));
    o.y = hm.y + w * (2.f * cn * (cc * hm.y - Sv.y) + 2.f * (A * hm.y - B.y));
    o.z = hm.z + w * (2.f * cn * (cc * hm.z - Sv.z) + 2.f * (A * hm.z - B.z));
    o.w = hm.w + w * (2.f * cn * (cc * hm.w - Sv.w) + 2.f * (A * hm.w - B.w));
    *(float4*)(out + idx4) = o;
}

extern "C" void kernel_launch(void* const* d_in, const int* in_sizes, int n_in,
                              void* d_out, int out_size, void* d_ws, size_t ws_size,
                              hipStream_t stream) {
    const float* x    = (const float*)d_in[0];
    const int*   ei   = (const int*)d_in[1];
    const float* wptr = (const float*)d_in[2];
    const float* Tptr = (const float*)d_in[3];
    const float* W    = (const float*)d_in[4];
    const float* b    = (const float*)d_in[5];
    float* out = (float*)d_out;

    const int N  = in_sizes[0] / DIN;   // 100000
    const int E  = in_sizes[1] / 2;     // 1000000
    const int NE = N * DOUT;
    const int* src = ei;
    const int* dst = ei + E;

    const int NBUK = (N + BW - 1) / BW;         // 196
    const int NC   = (E + EPC - 1) / EPC;       // 245
    const int M    = NBUK * NC;
    const int M2   = 2 * M;
    const int NBs  = (M2 + 255) / 256;          // <= 1024

    // workspace layout
    float*    h0s  = (float*)d_ws;                    // NE (reused as S later)
    float*    h    = h0s + NE;                        // NE
    int2*     bkt  = (int2*)(h + NE);                 // E int2 (8 MB, reused per dir)
    int*      pay1 = (int*)(bkt + E);                 // E (in-CSR payload: src ids)
    int*      pay2 = pay1 + E;                        // E (out-CSR payload: dst ids)
    unsigned* counts = (unsigned*)(pay2 + E);         // 2*M
    unsigned* bsum = counts + M2;                     // <=1024
    unsigned* off1 = bsum + 1024;                     // N+1
    unsigned* off2 = off1 + N + 1;                    // N+1
    unsigned* cnt  = off2 + N + 1;                    // N
    float*    e    = (float*)(cnt + N);               // N
    float*    c    = e + N;                           // N
    float*    dinv = c + N;                           // N
    float*    part = dinv + N;                        // 3*NSTATB
    float*    st   = part + 3 * NSTATB;               // 3
    float*    S    = h0s;                             // reuse after k_agg

    // W fragment buffers (16B-aligned), 16 KB each
    uintptr_t fb = (uintptr_t)(st + 3);
    fb = (fb + 15) & ~(uintptr_t)15;
    short8v* whf = (short8v*)fb;                      // [16][64] short8
    short8v* wlf = whf + 16 * 64;

    const int nodeG = (N + 15) / 16;    // 16 nodes per 256-thread block
    const int nodeBlocks = (N + 255) / 256;

    // W fragment pack (independent of everything else)
    k_prepw<<<1, 256, 0, stream>>>(W, whf, wlf);

    // build both direction counts + one combined scan
    k_countboth<<<NC, 256, 0, stream>>>(src, dst, counts, NBUK, NC, E);
    k_scanA<<<NBs, 256, 0, stream>>>(counts, bsum, M2);
    k_scan2<<<1, 1024, 0, stream>>>(bsum, NBs);
    k_scanC<<<NBs, 256, 0, stream>>>(counts, bsum, M2);

    // direction 0: in-CSR (key=dst, payload=src) -> off1/pay1 + cnt/dinv
    k_bucket<<<NC, 256, 0, stream>>>(dst, src, counts, 0, 0u, bkt, NBUK, NC, E);
    k_csr<<<NBUK, 256, 0, stream>>>(bkt, counts, off1, pay1, cnt, dinv,
                                    0, 0u, NBUK, NC, N, E);
    // direction 1: out-CSR (key=src, payload=dst) -> off2/pay2
    k_bucket<<<NC, 256, 0, stream>>>(src, dst, counts, M, (unsigned)E, bkt, NBUK, NC, E);
    k_csr<<<NBUK, 256, 0, stream>>>(bkt, counts, off2, pay2, nullptr, nullptr,
                                    M, (unsigned)E, NBUK, NC, N, E);

    k_gemm<<<(N + 63) / 64, 256, 0, stream>>>(x, whf, wlf, dinv, h0s, N);
    k_agg<<<nodeG, 256, 0, stream>>>(off1, pay1, dinv, h0s, b, h, N);
    k_energy<<<nodeG, 256, 0, stream>>>(off1, pay1, h, e, S, N);
    k_stats1<<<NSTATB, 256, 0, stream>>>(e, Tptr, part, N);
    k_stats2<<<1, 256, 0, stream>>>(part, st, NSTATB);
    k_coef<<<nodeBlocks, 256, 0, stream>>>(e, Tptr, st, c, N);
    k_grad_final<<<nodeG, 256, 0, stream>>>(off2, pay2, c, h, S, cnt, wptr, out, N);
}

// Round 11
// 293.060 us; speedup vs baseline: 1.2143x; 1.0903x over previous
//
#include <hip/hip_runtime.h>

#define DIN  128
#define DOUT 64
#define BW   512    // nodes per bucket (power of 2)
#define BSH  9      // log2(BW)
#define EPC  4096   // edges per chunk
#define NSTATB 400  // stat partial blocks

typedef short short8v __attribute__((ext_vector_type(8)));   // 8 bf16 (4 VGPRs)
typedef float f32x4 __attribute__((ext_vector_type(4)));

// ---------- bf16 helpers ----------
__device__ __forceinline__ float bf2f(unsigned short u) {
    return __uint_as_float((unsigned)u << 16);
}
__device__ __forceinline__ unsigned short f2bf(float f) {
    unsigned u = __float_as_uint(f);
    u += 0x7FFFu + ((u >> 16) & 1u);     // RNE
    return (unsigned short)(u >> 16);
}
__device__ __forceinline__ float4 bf4(ushort4 u) {
    return make_float4(bf2f(u.x), bf2f(u.y), bf2f(u.z), bf2f(u.w));
}

// ---------- K1: per-chunk, per-bucket histograms for BOTH directions ----------
__global__ __launch_bounds__(256) void k_countboth(const int* __restrict__ src,
                                                   const int* __restrict__ dst,
                                                   unsigned* __restrict__ counts,
                                                   int NBUK, int NC, int E) {
    __shared__ int h0[256], h1[256];
    for (int j = threadIdx.x; j < NBUK; j += 256) { h0[j] = 0; h1[j] = 0; }
    __syncthreads();
    int start = blockIdx.x * EPC;
    int end = min(start + EPC, E);
    for (int i = start + threadIdx.x; i < end; i += 256) {
        atomicAdd(&h0[dst[i] >> BSH], 1);
        atomicAdd(&h1[src[i] >> BSH], 1);
    }
    __syncthreads();
    int M = NBUK * NC;
    for (int j = threadIdx.x; j < NBUK; j += 256) {
        counts[j * NC + blockIdx.x]     = (unsigned)h0[j];
        counts[M + j * NC + blockIdx.x] = (unsigned)h1[j];
    }
}

// ---------- generic 3-kernel exclusive scan ----------
__global__ __launch_bounds__(256) void k_scanA(const unsigned* __restrict__ data,
                                               unsigned* __restrict__ bsums, int n) {
    __shared__ unsigned s[256];
    int i = blockIdx.x * 256 + threadIdx.x;
    s[threadIdx.x] = (i < n) ? data[i] : 0u;
    __syncthreads();
    for (int st = 128; st > 0; st >>= 1) {
        if (threadIdx.x < st) s[threadIdx.x] += s[threadIdx.x + st];
        __syncthreads();
    }
    if (threadIdx.x == 0) bsums[blockIdx.x] = s[0];
}

__global__ __launch_bounds__(1024) void k_scan2(unsigned* __restrict__ bsums, int NB) {
    __shared__ unsigned s[1024];
    int tid = threadIdx.x;
    unsigned v = (tid < NB) ? bsums[tid] : 0u;
    s[tid] = v;
    __syncthreads();
    for (int st = 1; st < 1024; st <<= 1) {
        unsigned t = (tid >= st) ? s[tid - st] : 0u;
        __syncthreads();
        s[tid] += t;
        __syncthreads();
    }
    if (tid < NB) bsums[tid] = s[tid] - v;   // exclusive
}

__global__ __launch_bounds__(256) void k_scanC(unsigned* __restrict__ data,
                                               const unsigned* __restrict__ bsums, int n) {
    __shared__ unsigned s[256];
    int i = blockIdx.x * 256 + threadIdx.x;
    unsigned v = (i < n) ? data[i] : 0u;
    s[threadIdx.x] = v;
    __syncthreads();
    for (int st = 1; st < 256; st <<= 1) {
        unsigned t = (threadIdx.x >= st) ? s[threadIdx.x - st] : 0u;
        __syncthreads();
        s[threadIdx.x] += t;
        __syncthreads();
    }
    if (i < n) data[i] = s[threadIdx.x] - v + bsums[blockIdx.x];
}

// ---------- K5: bucket-major reorder (coalesced block-private segments) ----------
__global__ __launch_bounds__(256) void k_bucket(const int* __restrict__ key,
                                                const int* __restrict__ other,
                                                const unsigned* __restrict__ counts,
                                                int dirOff, unsigned dirBase,
                                                int2* __restrict__ bucketed,
                                                int NBUK, int NC, int E) {
    __shared__ int cur[256];
    for (int j = threadIdx.x; j < NBUK; j += 256)
        cur[j] = (int)(counts[dirOff + j * NC + blockIdx.x] - dirBase);
    __syncthreads();
    int start = blockIdx.x * EPC;
    int end = min(start + EPC, E);
    for (int i = start + threadIdx.x; i < end; i += 256) {
        int k = key[i], o = other[i];
        int pos = atomicAdd(&cur[k >> BSH], 1);
        bucketed[pos] = make_int2(k, o);
    }
}

// ---------- K6: per-bucket CSR finalize — degrees, offsets, private scatter ----------
__global__ __launch_bounds__(256) void k_csr(const int2* __restrict__ bucketed,
                                             const unsigned* __restrict__ counts,
                                             unsigned* __restrict__ off,
                                             int* __restrict__ pay,
                                             unsigned* __restrict__ cnt,
                                             float* __restrict__ dinv,
                                             int dirOff, unsigned dirBase,
                                             int NBUK, int NC, int N, int E) {
    __shared__ int sH[BW];
    __shared__ int sS[2][BW];
    __shared__ int sC[BW];
    int b = blockIdx.x;
    int base = (int)(counts[dirOff + b * NC] - dirBase);
    int end  = (b + 1 < NBUK) ? (int)(counts[dirOff + (b + 1) * NC] - dirBase) : E;

    for (int j = threadIdx.x; j < BW; j += 256) sH[j] = 0;
    __syncthreads();
    for (int i = base + threadIdx.x; i < end; i += 256)
        atomicAdd(&sH[bucketed[i].x & (BW - 1)], 1);
    __syncthreads();
    for (int j = threadIdx.x; j < BW; j += 256) sS[0][j] = sH[j];
    __syncthreads();
    int pin = 0;
    for (int st = 1; st < BW; st <<= 1) {
        for (int j = threadIdx.x; j < BW; j += 256) {
            int v = sS[pin][j];
            if (j >= st) v += sS[pin][j - st];
            sS[pin ^ 1][j] = v;
        }
        __syncthreads();
        pin ^= 1;
    }
    int lo = b * BW;
    for (int j = threadIdx.x; j < BW; j += 256) {
        int excl = j ? sS[pin][j - 1] : 0;
        sC[j] = excl;
        int n = lo + j;
        if (n < N) {
            off[n] = (unsigned)(base + excl);
            if (cnt) {
                cnt[n] = (unsigned)sH[j];
                dinv[n] = rsqrtf((float)sH[j] + 1.f);
            }
        }
    }
    if (threadIdx.x == 0 && b == NBUK - 1) off[N] = (unsigned)E;
    __syncthreads();
    for (int i = base + threadIdx.x; i < end; i += 256) {
        int2 p = bucketed[i];
        int pos = base + atomicAdd(&sC[p.x & (BW - 1)], 1);
        pay[pos] = p.y;
    }
}

// ---------- bf16 split helpers (for MFMA gemm) ----------
__device__ __forceinline__ void split_bf16(float f, short& hi, short& lo) {
    unsigned u = __float_as_uint(f);
    hi = (short)(u >> 16);                              // truncate -> bf16 hi
    float hf = __uint_as_float(u & 0xFFFF0000u);
    float lf = f - hf;                                  // exact residual
    unsigned ul = __float_as_uint(lf);
    ul = ul + 0x7FFFu + ((ul >> 16) & 1u);              // RNE
    lo = (short)(ul >> 16);
}

// ---------- K7a: pack W into MFMA B-fragments (hi/lo), lane-linear ----------
__global__ __launch_bounds__(256) void k_prepw(const float* __restrict__ W,
                                               short8v* __restrict__ whf,
                                               short8v* __restrict__ wlf) {
    for (int idx = threadIdx.x; idx < 16 * 64; idx += 256) {
        int l = idx & 63;
        int ntkst = idx >> 6;          // = kst*4 + nt
        int kst = ntkst >> 2;
        int nt = ntkst & 3;
        int g = l >> 4;
        int c = nt * 16 + (l & 15);
        short8v hs, ls;
#pragma unroll
        for (int i = 0; i < 8; ++i) {
            float f = W[(size_t)(kst * 32 + g * 8 + i) * DOUT + c];
            short hi, lo;
            split_bf16(f, hi, lo);
            hs[i] = hi;
            ls[i] = lo;
        }
        whf[idx] = hs;
        wlf[idx] = ls;
    }
}

// ---------- K7: h0s = dinv[n] * (x[n] @ W)  via split-bf16 MFMA ----------
// (R10, verified): 3-term bf16 split on the matrix core; zero LDS/barriers;
// C/D layout col=lane&15, row=(lane>>4)*4+reg (m89-verified).
__global__ __launch_bounds__(256) void k_gemm(const float* __restrict__ x,
                                              const short8v* __restrict__ whf,
                                              const short8v* __restrict__ wlf,
                                              const float* __restrict__ dinv,
                                              float* __restrict__ h0s, int N) {
    int l = threadIdx.x & 63;
    int w = threadIdx.x >> 6;              // wave 0..3
    int r0 = blockIdx.x * 64 + w * 16;     // wave's 16-row tile
    int g = l >> 4;
    int arow = r0 + (l & 15);
    int arc = min(arow, N - 1);
    const float* xr = x + (size_t)arc * DIN + g * 8;

    f32x4 acc0 = {0.f, 0.f, 0.f, 0.f};
    f32x4 acc1 = {0.f, 0.f, 0.f, 0.f};
    f32x4 acc2 = {0.f, 0.f, 0.f, 0.f};
    f32x4 acc3 = {0.f, 0.f, 0.f, 0.f};

#pragma unroll
    for (int kst = 0; kst < 4; ++kst) {
        float4 a0 = *(const float4*)(xr + kst * 32);
        float4 a1 = *(const float4*)(xr + kst * 32 + 4);
        short8v ah, al;
        {
            short hi, lo;
            split_bf16(a0.x, hi, lo); ah[0] = hi; al[0] = lo;
            split_bf16(a0.y, hi, lo); ah[1] = hi; al[1] = lo;
            split_bf16(a0.z, hi, lo); ah[2] = hi; al[2] = lo;
            split_bf16(a0.w, hi, lo); ah[3] = hi; al[3] = lo;
            split_bf16(a1.x, hi, lo); ah[4] = hi; al[4] = lo;
            split_bf16(a1.y, hi, lo); ah[5] = hi; al[5] = lo;
            split_bf16(a1.z, hi, lo); ah[6] = hi; al[6] = lo;
            split_bf16(a1.w, hi, lo); ah[7] = hi; al[7] = lo;
        }
        int fb = kst * 4 * 64 + l;
        short8v bh0 = whf[fb + 0 * 64];
        short8v bl0 = wlf[fb + 0 * 64];
        short8v bh1 = whf[fb + 1 * 64];
        short8v bl1 = wlf[fb + 1 * 64];
        short8v bh2 = whf[fb + 2 * 64];
        short8v bl2 = wlf[fb + 2 * 64];
        short8v bh3 = whf[fb + 3 * 64];
        short8v bl3 = wlf[fb + 3 * 64];
        acc0 = __builtin_amdgcn_mfma_f32_16x16x32_bf16(ah, bh0, acc0, 0, 0, 0);
        acc0 = __builtin_amdgcn_mfma_f32_16x16x32_bf16(al, bh0, acc0, 0, 0, 0);
        acc0 = __builtin_amdgcn_mfma_f32_16x16x32_bf16(ah, bl0, acc0, 0, 0, 0);
        acc1 = __builtin_amdgcn_mfma_f32_16x16x32_bf16(ah, bh1, acc1, 0, 0, 0);
        acc1 = __builtin_amdgcn_mfma_f32_16x16x32_bf16(al, bh1, acc1, 0, 0, 0);
        acc1 = __builtin_amdgcn_mfma_f32_16x16x32_bf16(ah, bl1, acc1, 0, 0, 0);
        acc2 = __builtin_amdgcn_mfma_f32_16x16x32_bf16(ah, bh2, acc2, 0, 0, 0);
        acc2 = __builtin_amdgcn_mfma_f32_16x16x32_bf16(al, bh2, acc2, 0, 0, 0);
        acc2 = __builtin_amdgcn_mfma_f32_16x16x32_bf16(ah, bl2, acc2, 0, 0, 0);
        acc3 = __builtin_amdgcn_mfma_f32_16x16x32_bf16(ah, bh3, acc3, 0, 0, 0);
        acc3 = __builtin_amdgcn_mfma_f32_16x16x32_bf16(al, bh3, acc3, 0, 0, 0);
        acc3 = __builtin_amdgcn_mfma_f32_16x16x32_bf16(ah, bl3, acc3, 0, 0, 0);
    }

    // C/D: col = l&15, row = g*4 + i  (m89-verified)
    int cbase = l & 15;
#pragma unroll
    for (int i = 0; i < 4; ++i) {
        int n = r0 + g * 4 + i;
        if (n < N) {
            float dv = dinv[n];
            float* o = h0s + (size_t)n * DOUT + cbase;
            o[0]  = acc0[i] * dv;
            o[16] = acc1[i] * dv;
            o[32] = acc2[i] * dv;
            o[48] = acc3[i] * dv;
        }
    }
}

// ---------- K8: gather agg + fused combine; ALSO writes bf16 mirror hb ----------
// h stays fp32 (output backbone). hb feeds the error-tolerant gathers in
// k_energy/k_grad_final (every consumer multiplies by c ~ 1e-4).
__global__ __launch_bounds__(256) void k_agg(const unsigned* __restrict__ off,
                                             const int* __restrict__ pay,
                                             const float* __restrict__ dinv,
                                             const float* __restrict__ h0s,
                                             const float* __restrict__ b,
                                             float* __restrict__ h,
                                             unsigned short* __restrict__ hb, int N) {
    int t = threadIdx.x;
    int grp = t >> 4;          // 0..15
    int q = t & 15;
    int n = blockIdx.x * 16 + grp;
    if (n >= N) return;
    unsigned beg = off[n], end = off[n + 1];
    float4 acc = make_float4(0.f, 0.f, 0.f, 0.f);
    for (unsigned base2 = beg; base2 < end; base2 += 16) {
        unsigned idx = base2 + q;
        int pd = (idx < end) ? pay[idx] : 0;
        int jmax = (int)min(16u, end - base2);
        int j = 0;
        for (; j + 8 <= jmax; j += 8) {
            int s0 = __shfl(pd, j + 0, 16);
            int s1 = __shfl(pd, j + 1, 16);
            int s2 = __shfl(pd, j + 2, 16);
            int s3 = __shfl(pd, j + 3, 16);
            int s4 = __shfl(pd, j + 4, 16);
            int s5 = __shfl(pd, j + 5, 16);
            int s6 = __shfl(pd, j + 6, 16);
            int s7 = __shfl(pd, j + 7, 16);
            float4 a0 = *(const float4*)(h0s + (size_t)s0 * DOUT + 4 * q);
            float4 a1 = *(const float4*)(h0s + (size_t)s1 * DOUT + 4 * q);
            float4 a2 = *(const float4*)(h0s + (size_t)s2 * DOUT + 4 * q);
            float4 a3 = *(const float4*)(h0s + (size_t)s3 * DOUT + 4 * q);
            float4 a4 = *(const float4*)(h0s + (size_t)s4 * DOUT + 4 * q);
            float4 a5 = *(const float4*)(h0s + (size_t)s5 * DOUT + 4 * q);
            float4 a6 = *(const float4*)(h0s + (size_t)s6 * DOUT + 4 * q);
            float4 a7 = *(const float4*)(h0s + (size_t)s7 * DOUT + 4 * q);
            acc.x += ((a0.x + a1.x) + (a2.x + a3.x)) + ((a4.x + a5.x) + (a6.x + a7.x));
            acc.y += ((a0.y + a1.y) + (a2.y + a3.y)) + ((a4.y + a5.y) + (a6.y + a7.y));
            acc.z += ((a0.z + a1.z) + (a2.z + a3.z)) + ((a4.z + a5.z) + (a6.z + a7.z));
            acc.w += ((a0.w + a1.w) + (a2.w + a3.w)) + ((a4.w + a5.w) + (a6.w + a7.w));
        }
        for (; j + 4 <= jmax; j += 4) {
            int s0 = __shfl(pd, j + 0, 16);
            int s1 = __shfl(pd, j + 1, 16);
            int s2 = __shfl(pd, j + 2, 16);
            int s3 = __shfl(pd, j + 3, 16);
            float4 a0 = *(const float4*)(h0s + (size_t)s0 * DOUT + 4 * q);
            float4 a1 = *(const float4*)(h0s + (size_t)s1 * DOUT + 4 * q);
            float4 a2 = *(const float4*)(h0s + (size_t)s2 * DOUT + 4 * q);
            float4 a3 = *(const float4*)(h0s + (size_t)s3 * DOUT + 4 * q);
            acc.x += (a0.x + a1.x) + (a2.x + a3.x);
            acc.y += (a0.y + a1.y) + (a2.y + a3.y);
            acc.z += (a0.z + a1.z) + (a2.z + a3.z);
            acc.w += (a0.w + a1.w) + (a2.w + a3.w);
        }
        for (; j < jmax; ++j) {
            int s = __shfl(pd, j, 16);
            float4 a = *(const float4*)(h0s + (size_t)s * DOUT + 4 * q);
            acc.x += a.x; acc.y += a.y; acc.z += a.z; acc.w += a.w;
        }
    }
    float dv = dinv[n];
    float4 hs = *(const float4*)(h0s + (size_t)n * DOUT + 4 * q);
    float4 bv = *(const float4*)(b + 4 * q);
    float4 o;
    o.x = dv * (acc.x + hs.x) + bv.x;
    o.y = dv * (acc.y + hs.y) + bv.y;
    o.z = dv * (acc.z + hs.z) + bv.z;
    o.w = dv * (acc.w + hs.w) + bv.w;
    *(float4*)(h + (size_t)n * DOUT + 4 * q) = o;
    ushort4 ob;
    ob.x = f2bf(o.x); ob.y = f2bf(o.y); ob.z = f2bf(o.z); ob.w = f2bf(o.w);
    *(ushort4*)(hb + (size_t)n * DOUT + 4 * q) = ob;
}

// ---------- K9: gather energy + S — neighbor rows from bf16 mirror ----------
__global__ __launch_bounds__(256) void k_energy(const unsigned* __restrict__ off,
                                                const int* __restrict__ pay,
                                                const float* __restrict__ h,
                                                const unsigned short* __restrict__ hb,
                                                float* __restrict__ e,
                                                float* __restrict__ S, int N) {
    int t = threadIdx.x;
    int grp = t >> 4;
    int q = t & 15;
    int n = blockIdx.x * 16 + grp;
    if (n >= N) return;
    unsigned beg = off[n], end = off[n + 1];
    float4 hm = *(const float4*)(h + (size_t)n * DOUT + 4 * q);
    float4 Sa = make_float4(0.f, 0.f, 0.f, 0.f);
    float esum = 0.f;
#define EACC(a)                                                                \
    {                                                                          \
        Sa.x += a.x; Sa.y += a.y; Sa.z += a.z; Sa.w += a.w;                    \
        float dx = hm.x - a.x, dy = hm.y - a.y, dz = hm.z - a.z, dw = hm.w - a.w; \
        esum += dx * dx + dy * dy + dz * dz + dw * dw;                         \
    }
    for (unsigned base2 = beg; base2 < end; base2 += 16) {
        unsigned idx = base2 + q;
        int pd = (idx < end) ? pay[idx] : 0;
        int jmax = (int)min(16u, end - base2);
        int j = 0;
        for (; j + 8 <= jmax; j += 8) {
            int s0 = __shfl(pd, j + 0, 16);
            int s1 = __shfl(pd, j + 1, 16);
            int s2 = __shfl(pd, j + 2, 16);
            int s3 = __shfl(pd, j + 3, 16);
            int s4 = __shfl(pd, j + 4, 16);
            int s5 = __shfl(pd, j + 5, 16);
            int s6 = __shfl(pd, j + 6, 16);
            int s7 = __shfl(pd, j + 7, 16);
            ushort4 u0 = *(const ushort4*)(hb + (size_t)s0 * DOUT + 4 * q);
            ushort4 u1 = *(const ushort4*)(hb + (size_t)s1 * DOUT + 4 * q);
            ushort4 u2 = *(const ushort4*)(hb + (size_t)s2 * DOUT + 4 * q);
            ushort4 u3 = *(const ushort4*)(hb + (size_t)s3 * DOUT + 4 * q);
            ushort4 u4 = *(const ushort4*)(hb + (size_t)s4 * DOUT + 4 * q);
            ushort4 u5 = *(const ushort4*)(hb + (size_t)s5 * DOUT + 4 * q);
            ushort4 u6 = *(const ushort4*)(hb + (size_t)s6 * DOUT + 4 * q);
            ushort4 u7 = *(const ushort4*)(hb + (size_t)s7 * DOUT + 4 * q);
            float4 a0 = bf4(u0); float4 a1 = bf4(u1);
            float4 a2 = bf4(u2); float4 a3 = bf4(u3);
            float4 a4 = bf4(u4); float4 a5 = bf4(u5);
            float4 a6 = bf4(u6); float4 a7 = bf4(u7);
            EACC(a0) EACC(a1) EACC(a2) EACC(a3) EACC(a4) EACC(a5) EACC(a6) EACC(a7)
        }
        for (; j + 4 <= jmax; j += 4) {
            int s0 = __shfl(pd, j + 0, 16);
            int s1 = __shfl(pd, j + 1, 16);
            int s2 = __shfl(pd, j + 2, 16);
            int s3 = __shfl(pd, j + 3, 16);
            float4 a0 = bf4(*(const ushort4*)(hb + (size_t)s0 * DOUT + 4 * q));
            float4 a1 = bf4(*(const ushort4*)(hb + (size_t)s1 * DOUT + 4 * q));
            float4 a2 = bf4(*(const ushort4*)(hb + (size_t)s2 * DOUT + 4 * q));
            float4 a3 = bf4(*(const ushort4*)(hb + (size_t)s3 * DOUT + 4 * q));
            EACC(a0) EACC(a1) EACC(a2) EACC(a3)
        }
        for (; j < jmax; ++j) {
            int s = __shfl(pd, j, 16);
            float4 a = bf4(*(const ushort4*)(hb + (size_t)s * DOUT + 4 * q));
            EACC(a)
        }
    }
#undef EACC
#pragma unroll
    for (int m = 1; m <= 8; m <<= 1) esum += __shfl_xor(esum, m, 16);
    if (q == 0) e[n] = esum;
    *(float4*)(S + (size_t)n * DOUT + 4 * q) = Sa;
}

// ---------- K10: per-block softmax partials (m, Z, M) ----------
__global__ __launch_bounds__(256) void k_stats1(const float* __restrict__ e,
                                                const float* __restrict__ Tptr,
                                                float* __restrict__ part, int N) {
    float T = *Tptr;
    float m = -3.4e38f;
    int i0 = blockIdx.x * 256 + threadIdx.x;
    int stride = gridDim.x * 256;
    for (int i = i0; i < N; i += stride) m = fmaxf(m, -e[i] / T);
    __shared__ float sm[256];
    sm[threadIdx.x] = m;
    __syncthreads();
    for (int s = 128; s > 0; s >>= 1) {
        if (threadIdx.x < s) sm[threadIdx.x] = fmaxf(sm[threadIdx.x], sm[threadIdx.x + s]);
        __syncthreads();
    }
    float bm = sm[0];
    __syncthreads();
    float z = 0.f, mm = 0.f;
    for (int i = i0; i < N; i += stride) {
        float t = -e[i] / T - bm;
        float w = __expf(t);
        z += w;
        mm += w * t;
    }
    __shared__ float sz[256], sM[256];
    sz[threadIdx.x] = z;
    sM[threadIdx.x] = mm;
    __syncthreads();
    for (int s = 128; s > 0; s >>= 1) {
        if (threadIdx.x < s) {
            sz[threadIdx.x] += sz[threadIdx.x + s];
            sM[threadIdx.x] += sM[threadIdx.x + s];
        }
        __syncthreads();
    }
    if (threadIdx.x == 0) {
        part[blockIdx.x * 3 + 0] = bm;
        part[blockIdx.x * 3 + 1] = sz[0];
        part[blockIdx.x * 3 + 2] = sM[0];
    }
}

// ---------- K11: merge partials -> st = {m, Z, M} ----------
__global__ __launch_bounds__(256) void k_stats2(const float* __restrict__ part,
                                                float* __restrict__ st, int P) {
    __shared__ float sm[256];
    float m = -3.4e38f;
    for (int i = threadIdx.x; i < P; i += 256) m = fmaxf(m, part[3 * i]);
    sm[threadIdx.x] = m;
    __syncthreads();
    for (int s = 128; s > 0; s >>= 1) {
        if (threadIdx.x < s) sm[threadIdx.x] = fmaxf(sm[threadIdx.x], sm[threadIdx.x + s]);
        __syncthreads();
    }
    float gm = sm[0];
    __syncthreads();
    float Z = 0.f, M = 0.f;
    for (int i = threadIdx.x; i < P; i += 256) {
        float mb = part[3 * i], zb = part[3 * i + 1], Mb = part[3 * i + 2];
        float d = mb - gm, eb = __expf(d);
        Z += eb * zb;
        M += eb * (Mb + d * zb);
    }
    __shared__ float sz[256], sM2[256];
    sz[threadIdx.x] = Z;
    sM2[threadIdx.x] = M;
    __syncthreads();
    for (int s = 128; s > 0; s >>= 1) {
        if (threadIdx.x < s) {
            sz[threadIdx.x] += sz[threadIdx.x + s];
            sM2[threadIdx.x] += sM2[threadIdx.x + s];
        }
        __syncthreads();
    }
    if (threadIdx.x == 0) {
        st[0] = gm;
        st[1] = sz[0];
        st[2] = sM2[0];
    }
}

// ---------- K12: c_n = p_n * (logp_n + H) ----------
__global__ __launch_bounds__(256) void k_coef(const float* __restrict__ e,
                                              const float* __restrict__ Tptr,
                                              const float* __restrict__ st,
                                              float* __restrict__ c, int N) {
    int n = blockIdx.x * 256 + threadIdx.x;
    if (n >= N) return;
    float T = *Tptr;
    float gm = st[0], Z = st[1], M = st[2];
    float logZ = logf(Z);
    float H = logZ - M / Z;
    float t = -e[n] / T - gm;
    float lp = t - logZ;
    c[n] = expf(lp) * (lp + H);
}

// ---------- K13: out-CSR gather of A,B + fused final — rows from bf16 mirror ----------
__global__ __launch_bounds__(256) void k_grad_final(const unsigned* __restrict__ off,
                                                    const int* __restrict__ pay,
                                                    const float* __restrict__ c,
                                                    const float* __restrict__ h,
                                                    const unsigned short* __restrict__ hb,
                                                    const float* __restrict__ S,
                                                    const unsigned* __restrict__ cnt,
                                                    const float* __restrict__ wptr,
                                                    float* __restrict__ out, int N) {
    int t = threadIdx.x;
    int grp = t >> 4;
    int q = t & 15;
    int n = blockIdx.x * 16 + grp;
    if (n >= N) return;
    unsigned beg = off[n], end = off[n + 1];
    float A = 0.f;
    float4 B = make_float4(0.f, 0.f, 0.f, 0.f);
    for (unsigned base2 = beg; base2 < end; base2 += 16) {
        unsigned idx = base2 + q;
        int pd = 0;
        float cv = 0.f;
        if (idx < end) {
            pd = pay[idx];
            cv = c[pd];
        }
        int jmax = (int)min(16u, end - base2);
        int j = 0;
        for (; j + 8 <= jmax; j += 8) {
            int s0 = __shfl(pd, j + 0, 16);
            int s1 = __shfl(pd, j + 1, 16);
            int s2 = __shfl(pd, j + 2, 16);
            int s3 = __shfl(pd, j + 3, 16);
            int s4 = __shfl(pd, j + 4, 16);
            int s5 = __shfl(pd, j + 5, 16);
            int s6 = __shfl(pd, j + 6, 16);
            int s7 = __shfl(pd, j + 7, 16);
            float c0 = __shfl(cv, j + 0, 16);
            float c1 = __shfl(cv, j + 1, 16);
            float c2 = __shfl(cv, j + 2, 16);
            float c3 = __shfl(cv, j + 3, 16);
            float c4 = __shfl(cv, j + 4, 16);
            float c5 = __shfl(cv, j + 5, 16);
            float c6 = __shfl(cv, j + 6, 16);
            float c7 = __shfl(cv, j + 7, 16);
            float4 a0 = bf4(*(const ushort4*)(hb + (size_t)s0 * DOUT + 4 * q));
            float4 a1 = bf4(*(const ushort4*)(hb + (size_t)s1 * DOUT + 4 * q));
            float4 a2 = bf4(*(const ushort4*)(hb + (size_t)s2 * DOUT + 4 * q));
            float4 a3 = bf4(*(const ushort4*)(hb + (size_t)s3 * DOUT + 4 * q));
            float4 a4 = bf4(*(const ushort4*)(hb + (size_t)s4 * DOUT + 4 * q));
            float4 a5 = bf4(*(const ushort4*)(hb + (size_t)s5 * DOUT + 4 * q));
            float4 a6 = bf4(*(const ushort4*)(hb + (size_t)s6 * DOUT + 4 * q));
            float4 a7 = bf4(*(const ushort4*)(hb + (size_t)s7 * DOUT + 4 * q));
            A += ((c0 + c1) + (c2 + c3)) + ((c4 + c5) + (c6 + c7));
            B.x = fmaf(c0, a0.x, fmaf(c1, a1.x, fmaf(c2, a2.x, fmaf(c3, a3.x, B.x))));
            B.x = fmaf(c4, a4.x, fmaf(c5, a5.x, fmaf(c6, a6.x, fmaf(c7, a7.x, B.x))));
            B.y = fmaf(c0, a0.y, fmaf(c1, a1.y, fmaf(c2, a2.y, fmaf(c3, a3.y, B.y))));
            B.y = fmaf(c4, a4.y, fmaf(c5, a5.y, fmaf(c6, a6.y, fmaf(c7, a7.y, B.y))));
            B.z = fmaf(c0, a0.z, fmaf(c1, a1.z, fmaf(c2, a2.z, fmaf(c3, a3.z, B.z))));
            B.z = fmaf(c4, a4.z, fmaf(c5, a5.z, fmaf(c6, a6.z, fmaf(c7, a7.z, B.z))));
            B.w = fmaf(c0, a0.w, fmaf(c1, a1.w, fmaf(c2, a2.w, fmaf(c3, a3.w, B.w))));
            B.w = fmaf(c4, a4.w, fmaf(c5, a5.w, fmaf(c6, a6.w, fmaf(c7, a7.w, B.w))));
        }
        for (; j + 4 <= jmax; j += 4) {
            int s0 = __shfl(pd, j + 0, 16);
            int s1 = __shfl(pd, j + 1, 16);
            int s2 = __shfl(pd, j + 2, 16);
            int s3 = __shfl(pd, j + 3, 16);
            float c0 = __shfl(cv, j + 0, 16);
            float c1 = __shfl(cv, j + 1, 16);
            float c2 = __shfl(cv, j + 2, 16);
            float c3 = __shfl(cv, j + 3, 16);
            float4 a0 = bf4(*(const ushort4*)(hb + (size_t)s0 * DOUT + 4 * q));
            float4 a1 = bf4(*(const ushort4*)(hb + (size_t)s1 * DOUT + 4 * q));
            float4 a2 = bf4(*(const ushort4*)(hb + (size_t)s2 * DOUT + 4 * q));
            float4 a3 = bf4(*(const ushort4*)(hb + (size_t)s3 * DOUT + 4 * q));
            A += (c0 + c1) + (c2 + c3);
            B.x = fmaf(c0, a0.x, fmaf(c1, a1.x, fmaf(c2, a2.x, fmaf(c3, a3.x, B.x))));
            B.y = fmaf(c0, a0.y, fmaf(c1, a1.y, fmaf(c2, a2.y, fmaf(c3, a3.y, B.y))));
            B.z = fmaf(c0, a0.z, fmaf(c1, a1.z, fmaf(c2, a2.z, fmaf(c3, a3.z, B.z))));
            B.w = fmaf(c0, a0.w, fmaf(c1, a1.w, fmaf(c2, a2.w, fmaf(c3, a3.w, B.w))));
        }
        for (; j < jmax; ++j) {
            int s = __shfl(pd, j, 16);
            float cj = __shfl(cv, j, 16);
            float4 a = bf4(*(const ushort4*)(hb + (size_t)s * DOUT + 4 * q));
            A += cj;
            B.x = fmaf(cj, a.x, B.x);
            B.y = fmaf(cj, a.y, B.y);
            B.z = fmaf(cj, a.z, B.z);
            B.w = fmaf(cj, a.w, B.w);
        }
    }
    size_t idx4 = (size_t)n * DOUT + 4 * q;
    float4 hm = *(const float4*)(h + idx4);
    float4 Sv = *(const float4*)(S + idx4);
    float cn = c[n];
    float cc = (float)cnt[n];
    float w = *wptr;
    float4 o;
    o.x = hm.x + w * (2.f * cn * (cc * hm.x - Sv.x) + 2.f * (A * hm.x - B.x));
    o.y = hm.y + w * (2.f * cn * (cc * hm.y - Sv.y) + 2.f * (A * hm.y - B.y));
    o.z = hm.z + w * (2.f * cn * (cc * hm.z - Sv.z) + 2.f * (A * hm.z - B.z));
    o.w = hm.w + w * (2.f * cn * (cc * hm.w - Sv.w) + 2.f * (A * hm.w - B.w));
    *(float4*)(out + idx4) = o;
}

extern "C" void kernel_launch(void* const* d_in, const int* in_sizes, int n_in,
                              void* d_out, int out_size, void* d_ws, size_t ws_size,
                              hipStream_t stream) {
    const float* x    = (const float*)d_in[0];
    const int*   ei   = (const int*)d_in[1];
    const float* wptr = (const float*)d_in[2];
    const float* Tptr = (const float*)d_in[3];
    const float* W    = (const float*)d_in[4];
    const float* b    = (const float*)d_in[5];
    float* out = (float*)d_out;

    const int N  = in_sizes[0] / DIN;   // 100000
    const int E  = in_sizes[1] / 2;     // 1000000
    const int NE = N * DOUT;
    const int* src = ei;
    const int* dst = ei + E;

    const int NBUK = (N + BW - 1) / BW;         // 196
    const int NC   = (E + EPC - 1) / EPC;       // 245
    const int M    = NBUK * NC;
    const int M2   = 2 * M;
    const int NBs  = (M2 + 255) / 256;          // <= 1024

    // workspace layout
    float*    h0s  = (float*)d_ws;                    // NE (reused as S later)
    float*    h    = h0s + NE;                        // NE
    int2*     bkt  = (int2*)(h + NE);                 // E int2 (8 MB, reused per dir)
    int*      pay1 = (int*)(bkt + E);                 // E (in-CSR payload: src ids)
    int*      pay2 = pay1 + E;                        // E (out-CSR payload: dst ids)
    unsigned* counts = (unsigned*)(pay2 + E);         // 2*M
    unsigned* bsum = counts + M2;                     // <=1024
    unsigned* off1 = bsum + 1024;                     // N+1
    unsigned* off2 = off1 + N + 1;                    // N+1
    unsigned* cnt  = off2 + N + 1;                    // N
    float*    e    = (float*)(cnt + N);               // N
    float*    c    = e + N;                           // N
    float*    dinv = c + N;                           // N
    float*    part = dinv + N;                        // 3*NSTATB
    float*    st   = part + 3 * NSTATB;               // 3
    float*    S    = h0s;                             // reuse after k_agg

    // W fragment buffers (16B-aligned), 16 KB each, then bf16 h-mirror
    uintptr_t fb = (uintptr_t)(st + 3);
    fb = (fb + 15) & ~(uintptr_t)15;
    short8v* whf = (short8v*)fb;                      // [16][64] short8
    short8v* wlf = whf + 16 * 64;
    unsigned short* hb = (unsigned short*)(wlf + 16 * 64);  // NE bf16 (12.8 MB)

    const int nodeG = (N + 15) / 16;    // 16 nodes per 256-thread block
    const int nodeBlocks = (N + 255) / 256;

    // W fragment pack (independent of everything else)
    k_prepw<<<1, 256, 0, stream>>>(W, whf, wlf);

    // build both direction counts + one combined scan
    k_countboth<<<NC, 256, 0, stream>>>(src, dst, counts, NBUK, NC, E);
    k_scanA<<<NBs, 256, 0, stream>>>(counts, bsum, M2);
    k_scan2<<<1, 1024, 0, stream>>>(bsum, NBs);
    k_scanC<<<NBs, 256, 0, stream>>>(counts, bsum, M2);

    // direction 0: in-CSR (key=dst, payload=src) -> off1/pay1 + cnt/dinv
    k_bucket<<<NC, 256, 0, stream>>>(dst, src, counts, 0, 0u, bkt, NBUK, NC, E);
    k_csr<<<NBUK, 256, 0, stream>>>(bkt, counts, off1, pay1, cnt, dinv,
                                    0, 0u, NBUK, NC, N, E);
    // direction 1: out-CSR (key=src, payload=dst) -> off2/pay2
    k_bucket<<<NC, 256, 0, stream>>>(src, dst, counts, M, (unsigned)E, bkt, NBUK, NC, E);
    k_csr<<<NBUK, 256, 0, stream>>>(bkt, counts, off2, pay2, nullptr, nullptr,
                                    M, (unsigned)E, NBUK, NC, N, E);

    k_gemm<<<(N + 63) / 64, 256, 0, stream>>>(x, whf, wlf, dinv, h0s, N);
    k_agg<<<nodeG, 256, 0, stream>>>(off1, pay1, dinv, h0s, b, h, hb, N);
    k_energy<<<nodeG, 256, 0, stream>>>(off1, pay1, h, hb, e, S, N);
    k_stats1<<<NSTATB, 256, 0, stream>>>(e, Tptr, part, N);
    k_stats2<<<1, 256, 0, stream>>>(part, st, NSTATB);
    k_coef<<<nodeBlocks, 256, 0, stream>>>(e, Tptr, st, c, N);
    k_grad_final<<<nodeG, 256, 0, stream>>>(off2, pay2, c, h, hb, S, cnt, wptr, out, N);
}

// Round 12
// 282.634 us; speedup vs baseline: 1.2591x; 1.0369x over previous
//
#include <hip/hip_runtime.h>

#define DIN  128
#define DOUT 64
#define BW   512    // nodes per bucket (power of 2)
#define BSH  9      // log2(BW)
#define EPC  4096   // edges per chunk
#define NSTATB 400  // stat partial blocks

typedef short short8v __attribute__((ext_vector_type(8)));   // 8 bf16 (4 VGPRs)
typedef float f32x4 __attribute__((ext_vector_type(4)));

// ---------- bf16 helpers ----------
__device__ __forceinline__ float bf2f(unsigned short u) {
    return __uint_as_float((unsigned)u << 16);
}
__device__ __forceinline__ unsigned short f2bf(float f) {
    unsigned u = __float_as_uint(f);
    u += 0x7FFFu + ((u >> 16) & 1u);     // RNE
    return (unsigned short)(u >> 16);
}
__device__ __forceinline__ float4 bf4(ushort4 u) {
    return make_float4(bf2f(u.x), bf2f(u.y), bf2f(u.z), bf2f(u.w));
}

// ---------- K1: per-chunk, per-bucket histograms for BOTH directions ----------
__global__ __launch_bounds__(256) void k_countboth(const int* __restrict__ src,
                                                   const int* __restrict__ dst,
                                                   unsigned* __restrict__ counts,
                                                   int NBUK, int NC, int E) {
    __shared__ int h0[256], h1[256];
    for (int j = threadIdx.x; j < NBUK; j += 256) { h0[j] = 0; h1[j] = 0; }
    __syncthreads();
    int start = blockIdx.x * EPC;
    int end = min(start + EPC, E);
    for (int i = start + threadIdx.x; i < end; i += 256) {
        atomicAdd(&h0[dst[i] >> BSH], 1);
        atomicAdd(&h1[src[i] >> BSH], 1);
    }
    __syncthreads();
    int M = NBUK * NC;
    for (int j = threadIdx.x; j < NBUK; j += 256) {
        counts[j * NC + blockIdx.x]     = (unsigned)h0[j];
        counts[M + j * NC + blockIdx.x] = (unsigned)h1[j];
    }
}

// ---------- generic 3-kernel exclusive scan ----------
__global__ __launch_bounds__(256) void k_scanA(const unsigned* __restrict__ data,
                                               unsigned* __restrict__ bsums, int n) {
    __shared__ unsigned s[256];
    int i = blockIdx.x * 256 + threadIdx.x;
    s[threadIdx.x] = (i < n) ? data[i] : 0u;
    __syncthreads();
    for (int st = 128; st > 0; st >>= 1) {
        if (threadIdx.x < st) s[threadIdx.x] += s[threadIdx.x + st];
        __syncthreads();
    }
    if (threadIdx.x == 0) bsums[blockIdx.x] = s[0];
}

__global__ __launch_bounds__(1024) void k_scan2(unsigned* __restrict__ bsums, int NB) {
    __shared__ unsigned s[1024];
    int tid = threadIdx.x;
    unsigned v = (tid < NB) ? bsums[tid] : 0u;
    s[tid] = v;
    __syncthreads();
    for (int st = 1; st < 1024; st <<= 1) {
        unsigned t = (tid >= st) ? s[tid - st] : 0u;
        __syncthreads();
        s[tid] += t;
        __syncthreads();
    }
    if (tid < NB) bsums[tid] = s[tid] - v;   // exclusive
}

__global__ __launch_bounds__(256) void k_scanC(unsigned* __restrict__ data,
                                               const unsigned* __restrict__ bsums, int n) {
    __shared__ unsigned s[256];
    int i = blockIdx.x * 256 + threadIdx.x;
    unsigned v = (i < n) ? data[i] : 0u;
    s[threadIdx.x] = v;
    __syncthreads();
    for (int st = 1; st < 256; st <<= 1) {
        unsigned t = (threadIdx.x >= st) ? s[threadIdx.x - st] : 0u;
        __syncthreads();
        s[threadIdx.x] += t;
        __syncthreads();
    }
    if (i < n) data[i] = s[threadIdx.x] - v + bsums[blockIdx.x];
}

// ---------- K5: bucket-major reorder (coalesced block-private segments) ----------
__global__ __launch_bounds__(256) void k_bucket(const int* __restrict__ key,
                                                const int* __restrict__ other,
                                                const unsigned* __restrict__ counts,
                                                int dirOff, unsigned dirBase,
                                                int2* __restrict__ bucketed,
                                                int NBUK, int NC, int E) {
    __shared__ int cur[256];
    for (int j = threadIdx.x; j < NBUK; j += 256)
        cur[j] = (int)(counts[dirOff + j * NC + blockIdx.x] - dirBase);
    __syncthreads();
    int start = blockIdx.x * EPC;
    int end = min(start + EPC, E);
    for (int i = start + threadIdx.x; i < end; i += 256) {
        int k = key[i], o = other[i];
        int pos = atomicAdd(&cur[k >> BSH], 1);
        bucketed[pos] = make_int2(k, o);
    }
}

// ---------- K6: per-bucket CSR finalize — degrees, offsets, private scatter ----------
__global__ __launch_bounds__(256) void k_csr(const int2* __restrict__ bucketed,
                                             const unsigned* __restrict__ counts,
                                             unsigned* __restrict__ off,
                                             int* __restrict__ pay,
                                             unsigned* __restrict__ cnt,
                                             float* __restrict__ dinv,
                                             int dirOff, unsigned dirBase,
                                             int NBUK, int NC, int N, int E) {
    __shared__ int sH[BW];
    __shared__ int sS[2][BW];
    __shared__ int sC[BW];
    int b = blockIdx.x;
    int base = (int)(counts[dirOff + b * NC] - dirBase);
    int end  = (b + 1 < NBUK) ? (int)(counts[dirOff + (b + 1) * NC] - dirBase) : E;

    for (int j = threadIdx.x; j < BW; j += 256) sH[j] = 0;
    __syncthreads();
    for (int i = base + threadIdx.x; i < end; i += 256)
        atomicAdd(&sH[bucketed[i].x & (BW - 1)], 1);
    __syncthreads();
    for (int j = threadIdx.x; j < BW; j += 256) sS[0][j] = sH[j];
    __syncthreads();
    int pin = 0;
    for (int st = 1; st < BW; st <<= 1) {
        for (int j = threadIdx.x; j < BW; j += 256) {
            int v = sS[pin][j];
            if (j >= st) v += sS[pin][j - st];
            sS[pin ^ 1][j] = v;
        }
        __syncthreads();
        pin ^= 1;
    }
    int lo = b * BW;
    for (int j = threadIdx.x; j < BW; j += 256) {
        int excl = j ? sS[pin][j - 1] : 0;
        sC[j] = excl;
        int n = lo + j;
        if (n < N) {
            off[n] = (unsigned)(base + excl);
            if (cnt) {
                cnt[n] = (unsigned)sH[j];
                dinv[n] = rsqrtf((float)sH[j] + 1.f);
            }
        }
    }
    if (threadIdx.x == 0 && b == NBUK - 1) off[N] = (unsigned)E;
    __syncthreads();
    for (int i = base + threadIdx.x; i < end; i += 256) {
        int2 p = bucketed[i];
        int pos = base + atomicAdd(&sC[p.x & (BW - 1)], 1);
        pay[pos] = p.y;
    }
}

// ---------- bf16 split helpers (for MFMA gemm) ----------
__device__ __forceinline__ void split_bf16(float f, short& hi, short& lo) {
    unsigned u = __float_as_uint(f);
    hi = (short)(u >> 16);                              // truncate -> bf16 hi
    float hf = __uint_as_float(u & 0xFFFF0000u);
    float lf = f - hf;                                  // exact residual
    unsigned ul = __float_as_uint(lf);
    ul = ul + 0x7FFFu + ((ul >> 16) & 1u);              // RNE
    lo = (short)(ul >> 16);
}

// ---------- K7a: pack W into MFMA B-fragments (hi/lo), lane-linear ----------
__global__ __launch_bounds__(256) void k_prepw(const float* __restrict__ W,
                                               short8v* __restrict__ whf,
                                               short8v* __restrict__ wlf) {
    for (int idx = threadIdx.x; idx < 16 * 64; idx += 256) {
        int l = idx & 63;
        int ntkst = idx >> 6;          // = kst*4 + nt
        int kst = ntkst >> 2;
        int nt = ntkst & 3;
        int g = l >> 4;
        int c = nt * 16 + (l & 15);
        short8v hs, ls;
#pragma unroll
        for (int i = 0; i < 8; ++i) {
            float f = W[(size_t)(kst * 32 + g * 8 + i) * DOUT + c];
            short hi, lo;
            split_bf16(f, hi, lo);
            hs[i] = hi;
            ls[i] = lo;
        }
        whf[idx] = hs;
        wlf[idx] = ls;
    }
}

// ---------- K7: h0s = dinv[n] * (x[n] @ W)  via split-bf16 MFMA ----------
// (R10, verified): 3-term bf16 split on the matrix core; zero LDS/barriers;
// C/D layout col=lane&15, row=(lane>>4)*4+reg (m89-verified).
// R12: also writes bf16 mirror h0b for k_agg's neighbor gather (error
// budget: ~3e-4 added to h, an order below the 0.0078 absmax).
__global__ __launch_bounds__(256) void k_gemm(const float* __restrict__ x,
                                              const short8v* __restrict__ whf,
                                              const short8v* __restrict__ wlf,
                                              const float* __restrict__ dinv,
                                              float* __restrict__ h0s,
                                              unsigned short* __restrict__ h0b, int N) {
    int l = threadIdx.x & 63;
    int w = threadIdx.x >> 6;              // wave 0..3
    int r0 = blockIdx.x * 64 + w * 16;     // wave's 16-row tile
    int g = l >> 4;
    int arow = r0 + (l & 15);
    int arc = min(arow, N - 1);
    const float* xr = x + (size_t)arc * DIN + g * 8;

    f32x4 acc0 = {0.f, 0.f, 0.f, 0.f};
    f32x4 acc1 = {0.f, 0.f, 0.f, 0.f};
    f32x4 acc2 = {0.f, 0.f, 0.f, 0.f};
    f32x4 acc3 = {0.f, 0.f, 0.f, 0.f};

#pragma unroll
    for (int kst = 0; kst < 4; ++kst) {
        float4 a0 = *(const float4*)(xr + kst * 32);
        float4 a1 = *(const float4*)(xr + kst * 32 + 4);
        short8v ah, al;
        {
            short hi, lo;
            split_bf16(a0.x, hi, lo); ah[0] = hi; al[0] = lo;
            split_bf16(a0.y, hi, lo); ah[1] = hi; al[1] = lo;
            split_bf16(a0.z, hi, lo); ah[2] = hi; al[2] = lo;
            split_bf16(a0.w, hi, lo); ah[3] = hi; al[3] = lo;
            split_bf16(a1.x, hi, lo); ah[4] = hi; al[4] = lo;
            split_bf16(a1.y, hi, lo); ah[5] = hi; al[5] = lo;
            split_bf16(a1.z, hi, lo); ah[6] = hi; al[6] = lo;
            split_bf16(a1.w, hi, lo); ah[7] = hi; al[7] = lo;
        }
        int fb = kst * 4 * 64 + l;
        short8v bh0 = whf[fb + 0 * 64];
        short8v bl0 = wlf[fb + 0 * 64];
        short8v bh1 = whf[fb + 1 * 64];
        short8v bl1 = wlf[fb + 1 * 64];
        short8v bh2 = whf[fb + 2 * 64];
        short8v bl2 = wlf[fb + 2 * 64];
        short8v bh3 = whf[fb + 3 * 64];
        short8v bl3 = wlf[fb + 3 * 64];
        acc0 = __builtin_amdgcn_mfma_f32_16x16x32_bf16(ah, bh0, acc0, 0, 0, 0);
        acc0 = __builtin_amdgcn_mfma_f32_16x16x32_bf16(al, bh0, acc0, 0, 0, 0);
        acc0 = __builtin_amdgcn_mfma_f32_16x16x32_bf16(ah, bl0, acc0, 0, 0, 0);
        acc1 = __builtin_amdgcn_mfma_f32_16x16x32_bf16(ah, bh1, acc1, 0, 0, 0);
        acc1 = __builtin_amdgcn_mfma_f32_16x16x32_bf16(al, bh1, acc1, 0, 0, 0);
        acc1 = __builtin_amdgcn_mfma_f32_16x16x32_bf16(ah, bl1, acc1, 0, 0, 0);
        acc2 = __builtin_amdgcn_mfma_f32_16x16x32_bf16(ah, bh2, acc2, 0, 0, 0);
        acc2 = __builtin_amdgcn_mfma_f32_16x16x32_bf16(al, bh2, acc2, 0, 0, 0);
        acc2 = __builtin_amdgcn_mfma_f32_16x16x32_bf16(ah, bl2, acc2, 0, 0, 0);
        acc3 = __builtin_amdgcn_mfma_f32_16x16x32_bf16(ah, bh3, acc3, 0, 0, 0);
        acc3 = __builtin_amdgcn_mfma_f32_16x16x32_bf16(al, bh3, acc3, 0, 0, 0);
        acc3 = __builtin_amdgcn_mfma_f32_16x16x32_bf16(ah, bl3, acc3, 0, 0, 0);
    }

    // C/D: col = l&15, row = g*4 + i  (m89-verified)
    int cbase = l & 15;
#pragma unroll
    for (int i = 0; i < 4; ++i) {
        int n = r0 + g * 4 + i;
        if (n < N) {
            float dv = dinv[n];
            float v0 = acc0[i] * dv;
            float v1 = acc1[i] * dv;
            float v2 = acc2[i] * dv;
            float v3 = acc3[i] * dv;
            float* o = h0s + (size_t)n * DOUT + cbase;
            o[0]  = v0;
            o[16] = v1;
            o[32] = v2;
            o[48] = v3;
            unsigned short* ob = h0b + (size_t)n * DOUT + cbase;
            ob[0]  = f2bf(v0);
            ob[16] = f2bf(v1);
            ob[32] = f2bf(v2);
            ob[48] = f2bf(v3);
        }
    }
}

// ---------- K8: gather agg (bf16 neighbors) + fused combine; writes h + hb ----------
// Neighbor rows from h0b (bf16, halves gather bytes); self-term + dinv fp32.
__global__ __launch_bounds__(256) void k_agg(const unsigned* __restrict__ off,
                                             const int* __restrict__ pay,
                                             const float* __restrict__ dinv,
                                             const float* __restrict__ h0s,
                                             const unsigned short* __restrict__ h0b,
                                             const float* __restrict__ b,
                                             float* __restrict__ h,
                                             unsigned short* __restrict__ hb, int N) {
    int t = threadIdx.x;
    int grp = t >> 4;          // 0..15
    int q = t & 15;
    int n = blockIdx.x * 16 + grp;
    if (n >= N) return;
    unsigned beg = off[n], end = off[n + 1];
    float4 acc = make_float4(0.f, 0.f, 0.f, 0.f);
    for (unsigned base2 = beg; base2 < end; base2 += 16) {
        unsigned idx = base2 + q;
        int pd = (idx < end) ? pay[idx] : 0;
        int jmax = (int)min(16u, end - base2);
        int j = 0;
        for (; j + 8 <= jmax; j += 8) {
            int s0 = __shfl(pd, j + 0, 16);
            int s1 = __shfl(pd, j + 1, 16);
            int s2 = __shfl(pd, j + 2, 16);
            int s3 = __shfl(pd, j + 3, 16);
            int s4 = __shfl(pd, j + 4, 16);
            int s5 = __shfl(pd, j + 5, 16);
            int s6 = __shfl(pd, j + 6, 16);
            int s7 = __shfl(pd, j + 7, 16);
            float4 a0 = bf4(*(const ushort4*)(h0b + (size_t)s0 * DOUT + 4 * q));
            float4 a1 = bf4(*(const ushort4*)(h0b + (size_t)s1 * DOUT + 4 * q));
            float4 a2 = bf4(*(const ushort4*)(h0b + (size_t)s2 * DOUT + 4 * q));
            float4 a3 = bf4(*(const ushort4*)(h0b + (size_t)s3 * DOUT + 4 * q));
            float4 a4 = bf4(*(const ushort4*)(h0b + (size_t)s4 * DOUT + 4 * q));
            float4 a5 = bf4(*(const ushort4*)(h0b + (size_t)s5 * DOUT + 4 * q));
            float4 a6 = bf4(*(const ushort4*)(h0b + (size_t)s6 * DOUT + 4 * q));
            float4 a7 = bf4(*(const ushort4*)(h0b + (size_t)s7 * DOUT + 4 * q));
            acc.x += ((a0.x + a1.x) + (a2.x + a3.x)) + ((a4.x + a5.x) + (a6.x + a7.x));
            acc.y += ((a0.y + a1.y) + (a2.y + a3.y)) + ((a4.y + a5.y) + (a6.y + a7.y));
            acc.z += ((a0.z + a1.z) + (a2.z + a3.z)) + ((a4.z + a5.z) + (a6.z + a7.z));
            acc.w += ((a0.w + a1.w) + (a2.w + a3.w)) + ((a4.w + a5.w) + (a6.w + a7.w));
        }
        for (; j + 4 <= jmax; j += 4) {
            int s0 = __shfl(pd, j + 0, 16);
            int s1 = __shfl(pd, j + 1, 16);
            int s2 = __shfl(pd, j + 2, 16);
            int s3 = __shfl(pd, j + 3, 16);
            float4 a0 = bf4(*(const ushort4*)(h0b + (size_t)s0 * DOUT + 4 * q));
            float4 a1 = bf4(*(const ushort4*)(h0b + (size_t)s1 * DOUT + 4 * q));
            float4 a2 = bf4(*(const ushort4*)(h0b + (size_t)s2 * DOUT + 4 * q));
            float4 a3 = bf4(*(const ushort4*)(h0b + (size_t)s3 * DOUT + 4 * q));
            acc.x += (a0.x + a1.x) + (a2.x + a3.x);
            acc.y += (a0.y + a1.y) + (a2.y + a3.y);
            acc.z += (a0.z + a1.z) + (a2.z + a3.z);
            acc.w += (a0.w + a1.w) + (a2.w + a3.w);
        }
        for (; j < jmax; ++j) {
            int s = __shfl(pd, j, 16);
            float4 a = bf4(*(const ushort4*)(h0b + (size_t)s * DOUT + 4 * q));
            acc.x += a.x; acc.y += a.y; acc.z += a.z; acc.w += a.w;
        }
    }
    float dv = dinv[n];
    float4 hs = *(const float4*)(h0s + (size_t)n * DOUT + 4 * q);
    float4 bv = *(const float4*)(b + 4 * q);
    float4 o;
    o.x = dv * (acc.x + hs.x) + bv.x;
    o.y = dv * (acc.y + hs.y) + bv.y;
    o.z = dv * (acc.z + hs.z) + bv.z;
    o.w = dv * (acc.w + hs.w) + bv.w;
    *(float4*)(h + (size_t)n * DOUT + 4 * q) = o;
    ushort4 ob;
    ob.x = f2bf(o.x); ob.y = f2bf(o.y); ob.z = f2bf(o.z); ob.w = f2bf(o.w);
    *(ushort4*)(hb + (size_t)n * DOUT + 4 * q) = ob;
}

// ---------- K9: gather energy + S — neighbor rows from bf16 mirror ----------
__global__ __launch_bounds__(256) void k_energy(const unsigned* __restrict__ off,
                                                const int* __restrict__ pay,
                                                const float* __restrict__ h,
                                                const unsigned short* __restrict__ hb,
                                                float* __restrict__ e,
                                                float* __restrict__ S, int N) {
    int t = threadIdx.x;
    int grp = t >> 4;
    int q = t & 15;
    int n = blockIdx.x * 16 + grp;
    if (n >= N) return;
    unsigned beg = off[n], end = off[n + 1];
    float4 hm = *(const float4*)(h + (size_t)n * DOUT + 4 * q);
    float4 Sa = make_float4(0.f, 0.f, 0.f, 0.f);
    float esum = 0.f;
#define EACC(a)                                                                \
    {                                                                          \
        Sa.x += a.x; Sa.y += a.y; Sa.z += a.z; Sa.w += a.w;                    \
        float dx = hm.x - a.x, dy = hm.y - a.y, dz = hm.z - a.z, dw = hm.w - a.w; \
        esum += dx * dx + dy * dy + dz * dz + dw * dw;                         \
    }
    for (unsigned base2 = beg; base2 < end; base2 += 16) {
        unsigned idx = base2 + q;
        int pd = (idx < end) ? pay[idx] : 0;
        int jmax = (int)min(16u, end - base2);
        int j = 0;
        for (; j + 8 <= jmax; j += 8) {
            int s0 = __shfl(pd, j + 0, 16);
            int s1 = __shfl(pd, j + 1, 16);
            int s2 = __shfl(pd, j + 2, 16);
            int s3 = __shfl(pd, j + 3, 16);
            int s4 = __shfl(pd, j + 4, 16);
            int s5 = __shfl(pd, j + 5, 16);
            int s6 = __shfl(pd, j + 6, 16);
            int s7 = __shfl(pd, j + 7, 16);
            float4 a0 = bf4(*(const ushort4*)(hb + (size_t)s0 * DOUT + 4 * q));
            float4 a1 = bf4(*(const ushort4*)(hb + (size_t)s1 * DOUT + 4 * q));
            float4 a2 = bf4(*(const ushort4*)(hb + (size_t)s2 * DOUT + 4 * q));
            float4 a3 = bf4(*(const ushort4*)(hb + (size_t)s3 * DOUT + 4 * q));
            float4 a4 = bf4(*(const ushort4*)(hb + (size_t)s4 * DOUT + 4 * q));
            float4 a5 = bf4(*(const ushort4*)(hb + (size_t)s5 * DOUT + 4 * q));
            float4 a6 = bf4(*(const ushort4*)(hb + (size_t)s6 * DOUT + 4 * q));
            float4 a7 = bf4(*(const ushort4*)(hb + (size_t)s7 * DOUT + 4 * q));
            EACC(a0) EACC(a1) EACC(a2) EACC(a3) EACC(a4) EACC(a5) EACC(a6) EACC(a7)
        }
        for (; j + 4 <= jmax; j += 4) {
            int s0 = __shfl(pd, j + 0, 16);
            int s1 = __shfl(pd, j + 1, 16);
            int s2 = __shfl(pd, j + 2, 16);
            int s3 = __shfl(pd, j + 3, 16);
            float4 a0 = bf4(*(const ushort4*)(hb + (size_t)s0 * DOUT + 4 * q));
            float4 a1 = bf4(*(const ushort4*)(hb + (size_t)s1 * DOUT + 4 * q));
            float4 a2 = bf4(*(const ushort4*)(hb + (size_t)s2 * DOUT + 4 * q));
            float4 a3 = bf4(*(const ushort4*)(hb + (size_t)s3 * DOUT + 4 * q));
            EACC(a0) EACC(a1) EACC(a2) EACC(a3)
        }
        for (; j < jmax; ++j) {
            int s = __shfl(pd, j, 16);
            float4 a = bf4(*(const ushort4*)(hb + (size_t)s * DOUT + 4 * q));
            EACC(a)
        }
    }
#undef EACC
#pragma unroll
    for (int m = 1; m <= 8; m <<= 1) esum += __shfl_xor(esum, m, 16);
    if (q == 0) e[n] = esum;
    *(float4*)(S + (size_t)n * DOUT + 4 * q) = Sa;
}

// ---------- K10: per-block softmax partials (m, Z, M) ----------
__global__ __launch_bounds__(256) void k_stats1(const float* __restrict__ e,
                                                const float* __restrict__ Tptr,
                                                float* __restrict__ part, int N) {
    float T = *Tptr;
    float m = -3.4e38f;
    int i0 = blockIdx.x * 256 + threadIdx.x;
    int stride = gridDim.x * 256;
    for (int i = i0; i < N; i += stride) m = fmaxf(m, -e[i] / T);
    __shared__ float sm[256];
    sm[threadIdx.x] = m;
    __syncthreads();
    for (int s = 128; s > 0; s >>= 1) {
        if (threadIdx.x < s) sm[threadIdx.x] = fmaxf(sm[threadIdx.x], sm[threadIdx.x + s]);
        __syncthreads();
    }
    float bm = sm[0];
    __syncthreads();
    float z = 0.f, mm = 0.f;
    for (int i = i0; i < N; i += stride) {
        float t = -e[i] / T - bm;
        float w = __expf(t);
        z += w;
        mm += w * t;
    }
    __shared__ float sz[256], sM[256];
    sz[threadIdx.x] = z;
    sM[threadIdx.x] = mm;
    __syncthreads();
    for (int s = 128; s > 0; s >>= 1) {
        if (threadIdx.x < s) {
            sz[threadIdx.x] += sz[threadIdx.x + s];
            sM[threadIdx.x] += sM[threadIdx.x + s];
        }
        __syncthreads();
    }
    if (threadIdx.x == 0) {
        part[blockIdx.x * 3 + 0] = bm;
        part[blockIdx.x * 3 + 1] = sz[0];
        part[blockIdx.x * 3 + 2] = sM[0];
    }
}

// ---------- K11: merge partials -> st = {m, Z, M} ----------
__global__ __launch_bounds__(256) void k_stats2(const float* __restrict__ part,
                                                float* __restrict__ st, int P) {
    __shared__ float sm[256];
    float m = -3.4e38f;
    for (int i = threadIdx.x; i < P; i += 256) m = fmaxf(m, part[3 * i]);
    sm[threadIdx.x] = m;
    __syncthreads();
    for (int s = 128; s > 0; s >>= 1) {
        if (threadIdx.x < s) sm[threadIdx.x] = fmaxf(sm[threadIdx.x], sm[threadIdx.x + s]);
        __syncthreads();
    }
    float gm = sm[0];
    __syncthreads();
    float Z = 0.f, M = 0.f;
    for (int i = threadIdx.x; i < P; i += 256) {
        float mb = part[3 * i], zb = part[3 * i + 1], Mb = part[3 * i + 2];
        float d = mb - gm, eb = __expf(d);
        Z += eb * zb;
        M += eb * (Mb + d * zb);
    }
    __shared__ float sz[256], sM2[256];
    sz[threadIdx.x] = Z;
    sM2[threadIdx.x] = M;
    __syncthreads();
    for (int s = 128; s > 0; s >>= 1) {
        if (threadIdx.x < s) {
            sz[threadIdx.x] += sz[threadIdx.x + s];
            sM2[threadIdx.x] += sM2[threadIdx.x + s];
        }
        __syncthreads();
    }
    if (threadIdx.x == 0) {
        st[0] = gm;
        st[1] = sz[0];
        st[2] = sM2[0];
    }
}

// ---------- K12: c_n = p_n * (logp_n + H) ----------
__global__ __launch_bounds__(256) void k_coef(const float* __restrict__ e,
                                              const float* __restrict__ Tptr,
                                              const float* __restrict__ st,
                                              float* __restrict__ c, int N) {
    int n = blockIdx.x * 256 + threadIdx.x;
    if (n >= N) return;
    float T = *Tptr;
    float gm = st[0], Z = st[1], M = st[2];
    float logZ = logf(Z);
    float H = logZ - M / Z;
    float t = -e[n] / T - gm;
    float lp = t - logZ;
    c[n] = expf(lp) * (lp + H);
}

// ---------- K13: out-CSR gather of A,B + fused final — rows from bf16 mirror ----------
__global__ __launch_bounds__(256) void k_grad_final(const unsigned* __restrict__ off,
                                                    const int* __restrict__ pay,
                                                    const float* __restrict__ c,
                                                    const float* __restrict__ h,
                                                    const unsigned short* __restrict__ hb,
                                                    const float* __restrict__ S,
                                                    const unsigned* __restrict__ cnt,
                                                    const float* __restrict__ wptr,
                                                    float* __restrict__ out, int N) {
    int t = threadIdx.x;
    int grp = t >> 4;
    int q = t & 15;
    int n = blockIdx.x * 16 + grp;
    if (n >= N) return;
    unsigned beg = off[n], end = off[n + 1];
    float A = 0.f;
    float4 B = make_float4(0.f, 0.f, 0.f, 0.f);
    for (unsigned base2 = beg; base2 < end; base2 += 16) {
        unsigned idx = base2 + q;
        int pd = 0;
        float cv = 0.f;
        if (idx < end) {
            pd = pay[idx];
            cv = c[pd];
        }
        int jmax = (int)min(16u, end - base2);
        int j = 0;
        for (; j + 8 <= jmax; j += 8) {
            int s0 = __shfl(pd, j + 0, 16);
            int s1 = __shfl(pd, j + 1, 16);
            int s2 = __shfl(pd, j + 2, 16);
            int s3 = __shfl(pd, j + 3, 16);
            int s4 = __shfl(pd, j + 4, 16);
            int s5 = __shfl(pd, j + 5, 16);
            int s6 = __shfl(pd, j + 6, 16);
            int s7 = __shfl(pd, j + 7, 16);
            float c0 = __shfl(cv, j + 0, 16);
            float c1 = __shfl(cv, j + 1, 16);
            float c2 = __shfl(cv, j + 2, 16);
            float c3 = __shfl(cv, j + 3, 16);
            float c4 = __shfl(cv, j + 4, 16);
            float c5 = __shfl(cv, j + 5, 16);
            float c6 = __shfl(cv, j + 6, 16);
            float c7 = __shfl(cv, j + 7, 16);
            float4 a0 = bf4(*(const ushort4*)(hb + (size_t)s0 * DOUT + 4 * q));
            float4 a1 = bf4(*(const ushort4*)(hb + (size_t)s1 * DOUT + 4 * q));
            float4 a2 = bf4(*(const ushort4*)(hb + (size_t)s2 * DOUT + 4 * q));
            float4 a3 = bf4(*(const ushort4*)(hb + (size_t)s3 * DOUT + 4 * q));
            float4 a4 = bf4(*(const ushort4*)(hb + (size_t)s4 * DOUT + 4 * q));
            float4 a5 = bf4(*(const ushort4*)(hb + (size_t)s5 * DOUT + 4 * q));
            float4 a6 = bf4(*(const ushort4*)(hb + (size_t)s6 * DOUT + 4 * q));
            float4 a7 = bf4(*(const ushort4*)(hb + (size_t)s7 * DOUT + 4 * q));
            A += ((c0 + c1) + (c2 + c3)) + ((c4 + c5) + (c6 + c7));
            B.x = fmaf(c0, a0.x, fmaf(c1, a1.x, fmaf(c2, a2.x, fmaf(c3, a3.x, B.x))));
            B.x = fmaf(c4, a4.x, fmaf(c5, a5.x, fmaf(c6, a6.x, fmaf(c7, a7.x, B.x))));
            B.y = fmaf(c0, a0.y, fmaf(c1, a1.y, fmaf(c2, a2.y, fmaf(c3, a3.y, B.y))));
            B.y = fmaf(c4, a4.y, fmaf(c5, a5.y, fmaf(c6, a6.y, fmaf(c7, a7.y, B.y))));
            B.z = fmaf(c0, a0.z, fmaf(c1, a1.z, fmaf(c2, a2.z, fmaf(c3, a3.z, B.z))));
            B.z = fmaf(c4, a4.z, fmaf(c5, a5.z, fmaf(c6, a6.z, fmaf(c7, a7.z, B.z))));
            B.w = fmaf(c0, a0.w, fmaf(c1, a1.w, fmaf(c2, a2.w, fmaf(c3, a3.w, B.w))));
            B.w = fmaf(c4, a4.w, fmaf(c5, a5.w, fmaf(c6, a6.w, fmaf(c7, a7.w, B.w))));
        }
        for (; j + 4 <= jmax; j += 4) {
            int s0 = __shfl(pd, j + 0, 16);
            int s1 = __shfl(pd, j + 1, 16);
            int s2 = __shfl(pd, j + 2, 16);
            int s3 = __shfl(pd, j + 3, 16);
            float c0 = __shfl(cv, j + 0, 16);
            float c1 = __shfl(cv, j + 1, 16);
            float c2 = __shfl(cv, j + 2, 16);
            float c3 = __shfl(cv, j + 3, 16);
            float4 a0 = bf4(*(const ushort4*)(hb + (size_t)s0 * DOUT + 4 * q));
            float4 a1 = bf4(*(const ushort4*)(hb + (size_t)s1 * DOUT + 4 * q));
            float4 a2 = bf4(*(const ushort4*)(hb + (size_t)s2 * DOUT + 4 * q));
            float4 a3 = bf4(*(const ushort4*)(hb + (size_t)s3 * DOUT + 4 * q));
            A += (c0 + c1) + (c2 + c3);
            B.x = fmaf(c0, a0.x, fmaf(c1, a1.x, fmaf(c2, a2.x, fmaf(c3, a3.x, B.x))));
            B.y = fmaf(c0, a0.y, fmaf(c1, a1.y, fmaf(c2, a2.y, fmaf(c3, a3.y, B.y))));
            B.z = fmaf(c0, a0.z, fmaf(c1, a1.z, fmaf(c2, a2.z, fmaf(c3, a3.z, B.z))));
            B.w = fmaf(c0, a0.w, fmaf(c1, a1.w, fmaf(c2, a2.w, fmaf(c3, a3.w, B.w))));
        }
        for (; j < jmax; ++j) {
            int s = __shfl(pd, j, 16);
            float cj = __shfl(cv, j, 16);
            float4 a = bf4(*(const ushort4*)(hb + (size_t)s * DOUT + 4 * q));
            A += cj;
            B.x = fmaf(cj, a.x, B.x);
            B.y = fmaf(cj, a.y, B.y);
            B.z = fmaf(cj, a.z, B.z);
            B.w = fmaf(cj, a.w, B.w);
        }
    }
    size_t idx4 = (size_t)n * DOUT + 4 * q;
    float4 hm = *(const float4*)(h + idx4);
    float4 Sv = *(const float4*)(S + idx4);
    float cn = c[n];
    float cc = (float)cnt[n];
    float w = *wptr;
    float4 o;
    o.x = hm.x + w * (2.f * cn * (cc * hm.x - Sv.x) + 2.f * (A * hm.x - B.x));
    o.y = hm.y + w * (2.f * cn * (cc * hm.y - Sv.y) + 2.f * (A * hm.y - B.y));
    o.z = hm.z + w * (2.f * cn * (cc * hm.z - Sv.z) + 2.f * (A * hm.z - B.z));
    o.w = hm.w + w * (2.f * cn * (cc * hm.w - Sv.w) + 2.f * (A * hm.w - B.w));
    *(float4*)(out + idx4) = o;
}

extern "C" void kernel_launch(void* const* d_in, const int* in_sizes, int n_in,
                              void* d_out, int out_size, void* d_ws, size_t ws_size,
                              hipStream_t stream) {
    const float* x    = (const float*)d_in[0];
    const int*   ei   = (const int*)d_in[1];
    const float* wptr = (const float*)d_in[2];
    const float* Tptr = (const float*)d_in[3];
    const float* W    = (const float*)d_in[4];
    const float* b    = (const float*)d_in[5];
    float* out = (float*)d_out;

    const int N  = in_sizes[0] / DIN;   // 100000
    const int E  = in_sizes[1] / 2;     // 1000000
    const int NE = N * DOUT;
    const int* src = ei;
    const int* dst = ei + E;

    const int NBUK = (N + BW - 1) / BW;         // 196
    const int NC   = (E + EPC - 1) / EPC;       // 245
    const int M    = NBUK * NC;
    const int M2   = 2 * M;
    const int NBs  = (M2 + 255) / 256;          // <= 1024

    // workspace layout
    float*    h0s  = (float*)d_ws;                    // NE (reused as S later)
    float*    h    = h0s + NE;                        // NE
    int2*     bkt  = (int2*)(h + NE);                 // E int2 (8 MB, reused per dir)
    int*      pay1 = (int*)(bkt + E);                 // E (in-CSR payload: src ids)
    int*      pay2 = pay1 + E;                        // E (out-CSR payload: dst ids)
    unsigned* counts = (unsigned*)(pay2 + E);         // 2*M
    unsigned* bsum = counts + M2;                     // <=1024
    unsigned* off1 = bsum + 1024;                     // N+1
    unsigned* off2 = off1 + N + 1;                    // N+1
    unsigned* cnt  = off2 + N + 1;                    // N
    float*    e    = (float*)(cnt + N);               // N
    float*    c    = e + N;                           // N
    float*    dinv = c + N;                           // N
    float*    part = dinv + N;                        // 3*NSTATB
    float*    st   = part + 3 * NSTATB;               // 3
    float*    S    = h0s;                             // reuse after k_agg

    // W fragment buffers (16B-aligned), then bf16 mirrors of h and h0s
    uintptr_t fb = (uintptr_t)(st + 3);
    fb = (fb + 15) & ~(uintptr_t)15;
    short8v* whf = (short8v*)fb;                      // [16][64] short8
    short8v* wlf = whf + 16 * 64;
    unsigned short* hb  = (unsigned short*)(wlf + 16 * 64);  // NE bf16 (12.8 MB)
    unsigned short* h0b = hb + NE;                           // NE bf16 (12.8 MB)

    const int nodeG = (N + 15) / 16;    // 16 nodes per 256-thread block
    const int nodeBlocks = (N + 255) / 256;

    // W fragment pack (independent of everything else)
    k_prepw<<<1, 256, 0, stream>>>(W, whf, wlf);

    // build both direction counts + one combined scan
    k_countboth<<<NC, 256, 0, stream>>>(src, dst, counts, NBUK, NC, E);
    k_scanA<<<NBs, 256, 0, stream>>>(counts, bsum, M2);
    k_scan2<<<1, 1024, 0, stream>>>(bsum, NBs);
    k_scanC<<<NBs, 256, 0, stream>>>(counts, bsum, M2);

    // direction 0: in-CSR (key=dst, payload=src) -> off1/pay1 + cnt/dinv
    k_bucket<<<NC, 256, 0, stream>>>(dst, src, counts, 0, 0u, bkt, NBUK, NC, E);
    k_csr<<<NBUK, 256, 0, stream>>>(bkt, counts, off1, pay1, cnt, dinv,
                                    0, 0u, NBUK, NC, N, E);
    // direction 1: out-CSR (key=src, payload=dst) -> off2/pay2
    k_bucket<<<NC, 256, 0, stream>>>(src, dst, counts, M, (unsigned)E, bkt, NBUK, NC, E);
    k_csr<<<NBUK, 256, 0, stream>>>(bkt, counts, off2, pay2, nullptr, nullptr,
                                    M, (unsigned)E, NBUK, NC, N, E);

    k_gemm<<<(N + 63) / 64, 256, 0, stream>>>(x, whf, wlf, dinv, h0s, h0b, N);
    k_agg<<<nodeG, 256, 0, stream>>>(off1, pay1, dinv, h0s, h0b, b, h, hb, N);
    k_energy<<<nodeG, 256, 0, stream>>>(off1, pay1, h, hb, e, S, N);
    k_stats1<<<NSTATB, 256, 0, stream>>>(e, Tptr, part, N);
    k_stats2<<<1, 256, 0, stream>>>(part, st, NSTATB);
    k_coef<<<nodeBlocks, 256, 0, stream>>>(e, Tptr, st, c, N);
    k_grad_final<<<nodeG, 256, 0, stream>>>(off2, pay2, c, h, hb, S, cnt, wptr, out, N);
}

// Round 13
// 280.794 us; speedup vs baseline: 1.2673x; 1.0066x over previous
//
#include <hip/hip_runtime.h>

#define DIN  128
#define DOUT 64
#define BW   512    // nodes per bucket (power of 2)
#define BSH  9      // log2(BW)
#define EPC  4096   // edges per chunk
#define NSTATB 400  // stat partial blocks

typedef short short8v __attribute__((ext_vector_type(8)));   // 8 bf16 (4 VGPRs)
typedef float f32x4 __attribute__((ext_vector_type(4)));

// ---------- bf16 helpers ----------
__device__ __forceinline__ float bf2f(unsigned short u) {
    return __uint_as_float((unsigned)u << 16);
}
__device__ __forceinline__ unsigned short f2bf(float f) {
    unsigned u = __float_as_uint(f);
    u += 0x7FFFu + ((u >> 16) & 1u);     // RNE
    return (unsigned short)(u >> 16);
}
__device__ __forceinline__ float4 bf4(ushort4 u) {
    return make_float4(bf2f(u.x), bf2f(u.y), bf2f(u.z), bf2f(u.w));
}

// ---------- K1: per-chunk, per-bucket histograms for BOTH directions ----------
__global__ __launch_bounds__(256) void k_countboth(const int* __restrict__ src,
                                                   const int* __restrict__ dst,
                                                   unsigned* __restrict__ counts,
                                                   int NBUK, int NC, int E) {
    __shared__ int h0[256], h1[256];
    for (int j = threadIdx.x; j < NBUK; j += 256) { h0[j] = 0; h1[j] = 0; }
    __syncthreads();
    int start = blockIdx.x * EPC;
    int end = min(start + EPC, E);
    for (int i = start + threadIdx.x; i < end; i += 256) {
        atomicAdd(&h0[dst[i] >> BSH], 1);
        atomicAdd(&h1[src[i] >> BSH], 1);
    }
    __syncthreads();
    int M = NBUK * NC;
    for (int j = threadIdx.x; j < NBUK; j += 256) {
        counts[j * NC + blockIdx.x]     = (unsigned)h0[j];
        counts[M + j * NC + blockIdx.x] = (unsigned)h1[j];
    }
}

// ---------- generic 3-kernel exclusive scan ----------
__global__ __launch_bounds__(256) void k_scanA(const unsigned* __restrict__ data,
                                               unsigned* __restrict__ bsums, int n) {
    __shared__ unsigned s[256];
    int i = blockIdx.x * 256 + threadIdx.x;
    s[threadIdx.x] = (i < n) ? data[i] : 0u;
    __syncthreads();
    for (int st = 128; st > 0; st >>= 1) {
        if (threadIdx.x < st) s[threadIdx.x] += s[threadIdx.x + st];
        __syncthreads();
    }
    if (threadIdx.x == 0) bsums[blockIdx.x] = s[0];
}

__global__ __launch_bounds__(1024) void k_scan2(unsigned* __restrict__ bsums, int NB) {
    __shared__ unsigned s[1024];
    int tid = threadIdx.x;
    unsigned v = (tid < NB) ? bsums[tid] : 0u;
    s[tid] = v;
    __syncthreads();
    for (int st = 1; st < 1024; st <<= 1) {
        unsigned t = (tid >= st) ? s[tid - st] : 0u;
        __syncthreads();
        s[tid] += t;
        __syncthreads();
    }
    if (tid < NB) bsums[tid] = s[tid] - v;   // exclusive
}

__global__ __launch_bounds__(256) void k_scanC(unsigned* __restrict__ data,
                                               const unsigned* __restrict__ bsums, int n) {
    __shared__ unsigned s[256];
    int i = blockIdx.x * 256 + threadIdx.x;
    unsigned v = (i < n) ? data[i] : 0u;
    s[threadIdx.x] = v;
    __syncthreads();
    for (int st = 1; st < 256; st <<= 1) {
        unsigned t = (threadIdx.x >= st) ? s[threadIdx.x - st] : 0u;
        __syncthreads();
        s[threadIdx.x] += t;
        __syncthreads();
    }
    if (i < n) data[i] = s[threadIdx.x] - v + bsums[blockIdx.x];
}

// ---------- K5: bucket-major reorder (coalesced block-private segments) ----------
__global__ __launch_bounds__(256) void k_bucket(const int* __restrict__ key,
                                                const int* __restrict__ other,
                                                const unsigned* __restrict__ counts,
                                                int dirOff, unsigned dirBase,
                                                int2* __restrict__ bucketed,
                                                int NBUK, int NC, int E) {
    __shared__ int cur[256];
    for (int j = threadIdx.x; j < NBUK; j += 256)
        cur[j] = (int)(counts[dirOff + j * NC + blockIdx.x] - dirBase);
    __syncthreads();
    int start = blockIdx.x * EPC;
    int end = min(start + EPC, E);
    for (int i = start + threadIdx.x; i < end; i += 256) {
        int k = key[i], o = other[i];
        int pos = atomicAdd(&cur[k >> BSH], 1);
        bucketed[pos] = make_int2(k, o);
    }
}

// ---------- K6: per-bucket CSR finalize — degrees, offsets, private scatter ----------
__global__ __launch_bounds__(256) void k_csr(const int2* __restrict__ bucketed,
                                             const unsigned* __restrict__ counts,
                                             unsigned* __restrict__ off,
                                             int* __restrict__ pay,
                                             unsigned* __restrict__ cnt,
                                             float* __restrict__ dinv,
                                             int dirOff, unsigned dirBase,
                                             int NBUK, int NC, int N, int E) {
    __shared__ int sH[BW];
    __shared__ int sS[2][BW];
    __shared__ int sC[BW];
    int b = blockIdx.x;
    int base = (int)(counts[dirOff + b * NC] - dirBase);
    int end  = (b + 1 < NBUK) ? (int)(counts[dirOff + (b + 1) * NC] - dirBase) : E;

    for (int j = threadIdx.x; j < BW; j += 256) sH[j] = 0;
    __syncthreads();
    for (int i = base + threadIdx.x; i < end; i += 256)
        atomicAdd(&sH[bucketed[i].x & (BW - 1)], 1);
    __syncthreads();
    for (int j = threadIdx.x; j < BW; j += 256) sS[0][j] = sH[j];
    __syncthreads();
    int pin = 0;
    for (int st = 1; st < BW; st <<= 1) {
        for (int j = threadIdx.x; j < BW; j += 256) {
            int v = sS[pin][j];
            if (j >= st) v += sS[pin][j - st];
            sS[pin ^ 1][j] = v;
        }
        __syncthreads();
        pin ^= 1;
    }
    int lo = b * BW;
    for (int j = threadIdx.x; j < BW; j += 256) {
        int excl = j ? sS[pin][j - 1] : 0;
        sC[j] = excl;
        int n = lo + j;
        if (n < N) {
            off[n] = (unsigned)(base + excl);
            if (cnt) {
                cnt[n] = (unsigned)sH[j];
                dinv[n] = rsqrtf((float)sH[j] + 1.f);
            }
        }
    }
    if (threadIdx.x == 0 && b == NBUK - 1) off[N] = (unsigned)E;
    __syncthreads();
    for (int i = base + threadIdx.x; i < end; i += 256) {
        int2 p = bucketed[i];
        int pos = base + atomicAdd(&sC[p.x & (BW - 1)], 1);
        pay[pos] = p.y;
    }
}

// ---------- bf16 split helpers (for MFMA gemm) ----------
__device__ __forceinline__ void split_bf16(float f, short& hi, short& lo) {
    unsigned u = __float_as_uint(f);
    hi = (short)(u >> 16);                              // truncate -> bf16 hi
    float hf = __uint_as_float(u & 0xFFFF0000u);
    float lf = f - hf;                                  // exact residual
    unsigned ul = __float_as_uint(lf);
    ul = ul + 0x7FFFu + ((ul >> 16) & 1u);              // RNE
    lo = (short)(ul >> 16);
}

// ---------- K7a: pack W into MFMA B-fragments (hi/lo), lane-linear ----------
__global__ __launch_bounds__(256) void k_prepw(const float* __restrict__ W,
                                               short8v* __restrict__ whf,
                                               short8v* __restrict__ wlf) {
    for (int idx = threadIdx.x; idx < 16 * 64; idx += 256) {
        int l = idx & 63;
        int ntkst = idx >> 6;          // = kst*4 + nt
        int kst = ntkst >> 2;
        int nt = ntkst & 3;
        int g = l >> 4;
        int c = nt * 16 + (l & 15);
        short8v hs, ls;
#pragma unroll
        for (int i = 0; i < 8; ++i) {
            float f = W[(size_t)(kst * 32 + g * 8 + i) * DOUT + c];
            short hi, lo;
            split_bf16(f, hi, lo);
            hs[i] = hi;
            ls[i] = lo;
        }
        whf[idx] = hs;
        wlf[idx] = ls;
    }
}

// ---------- K7: h0s = dinv[n] * (x[n] @ W)  via split-bf16 MFMA ----------
// (R10, verified): 3-term bf16 split on the matrix core; zero LDS/barriers;
// C/D layout col=lane&15, row=(lane>>4)*4+reg (m89-verified).
// Writes fp32 h0s (self-term path) + bf16 mirror h0b (gather path).
__global__ __launch_bounds__(256) void k_gemm(const float* __restrict__ x,
                                              const short8v* __restrict__ whf,
                                              const short8v* __restrict__ wlf,
                                              const float* __restrict__ dinv,
                                              float* __restrict__ h0s,
                                              unsigned short* __restrict__ h0b, int N) {
    int l = threadIdx.x & 63;
    int w = threadIdx.x >> 6;              // wave 0..3
    int r0 = blockIdx.x * 64 + w * 16;     // wave's 16-row tile
    int g = l >> 4;
    int arow = r0 + (l & 15);
    int arc = min(arow, N - 1);
    const float* xr = x + (size_t)arc * DIN + g * 8;

    f32x4 acc0 = {0.f, 0.f, 0.f, 0.f};
    f32x4 acc1 = {0.f, 0.f, 0.f, 0.f};
    f32x4 acc2 = {0.f, 0.f, 0.f, 0.f};
    f32x4 acc3 = {0.f, 0.f, 0.f, 0.f};

#pragma unroll
    for (int kst = 0; kst < 4; ++kst) {
        float4 a0 = *(const float4*)(xr + kst * 32);
        float4 a1 = *(const float4*)(xr + kst * 32 + 4);
        short8v ah, al;
        {
            short hi, lo;
            split_bf16(a0.x, hi, lo); ah[0] = hi; al[0] = lo;
            split_bf16(a0.y, hi, lo); ah[1] = hi; al[1] = lo;
            split_bf16(a0.z, hi, lo); ah[2] = hi; al[2] = lo;
            split_bf16(a0.w, hi, lo); ah[3] = hi; al[3] = lo;
            split_bf16(a1.x, hi, lo); ah[4] = hi; al[4] = lo;
            split_bf16(a1.y, hi, lo); ah[5] = hi; al[5] = lo;
            split_bf16(a1.z, hi, lo); ah[6] = hi; al[6] = lo;
            split_bf16(a1.w, hi, lo); ah[7] = hi; al[7] = lo;
        }
        int fb = kst * 4 * 64 + l;
        short8v bh0 = whf[fb + 0 * 64];
        short8v bl0 = wlf[fb + 0 * 64];
        short8v bh1 = whf[fb + 1 * 64];
        short8v bl1 = wlf[fb + 1 * 64];
        short8v bh2 = whf[fb + 2 * 64];
        short8v bl2 = wlf[fb + 2 * 64];
        short8v bh3 = whf[fb + 3 * 64];
        short8v bl3 = wlf[fb + 3 * 64];
        acc0 = __builtin_amdgcn_mfma_f32_16x16x32_bf16(ah, bh0, acc0, 0, 0, 0);
        acc0 = __builtin_amdgcn_mfma_f32_16x16x32_bf16(al, bh0, acc0, 0, 0, 0);
        acc0 = __builtin_amdgcn_mfma_f32_16x16x32_bf16(ah, bl0, acc0, 0, 0, 0);
        acc1 = __builtin_amdgcn_mfma_f32_16x16x32_bf16(ah, bh1, acc1, 0, 0, 0);
        acc1 = __builtin_amdgcn_mfma_f32_16x16x32_bf16(al, bh1, acc1, 0, 0, 0);
        acc1 = __builtin_amdgcn_mfma_f32_16x16x32_bf16(ah, bl1, acc1, 0, 0, 0);
        acc2 = __builtin_amdgcn_mfma_f32_16x16x32_bf16(ah, bh2, acc2, 0, 0, 0);
        acc2 = __builtin_amdgcn_mfma_f32_16x16x32_bf16(al, bh2, acc2, 0, 0, 0);
        acc2 = __builtin_amdgcn_mfma_f32_16x16x32_bf16(ah, bl2, acc2, 0, 0, 0);
        acc3 = __builtin_amdgcn_mfma_f32_16x16x32_bf16(ah, bh3, acc3, 0, 0, 0);
        acc3 = __builtin_amdgcn_mfma_f32_16x16x32_bf16(al, bh3, acc3, 0, 0, 0);
        acc3 = __builtin_amdgcn_mfma_f32_16x16x32_bf16(ah, bl3, acc3, 0, 0, 0);
    }

    // C/D: col = l&15, row = g*4 + i  (m89-verified)
    int cbase = l & 15;
#pragma unroll
    for (int i = 0; i < 4; ++i) {
        int n = r0 + g * 4 + i;
        if (n < N) {
            float dv = dinv[n];
            float v0 = acc0[i] * dv;
            float v1 = acc1[i] * dv;
            float v2 = acc2[i] * dv;
            float v3 = acc3[i] * dv;
            float* o = h0s + (size_t)n * DOUT + cbase;
            o[0]  = v0;
            o[16] = v1;
            o[32] = v2;
            o[48] = v3;
            unsigned short* ob = h0b + (size_t)n * DOUT + cbase;
            ob[0]  = f2bf(v0);
            ob[16] = f2bf(v1);
            ob[32] = f2bf(v2);
            ob[48] = f2bf(v3);
        }
    }
}

// ---------- K8: gather agg (bf16 neighbors) + fused combine; writes h + hb ----------
__global__ __launch_bounds__(256) void k_agg(const unsigned* __restrict__ off,
                                             const int* __restrict__ pay,
                                             const float* __restrict__ dinv,
                                             const float* __restrict__ h0s,
                                             const unsigned short* __restrict__ h0b,
                                             const float* __restrict__ b,
                                             float* __restrict__ h,
                                             unsigned short* __restrict__ hb, int N) {
    int t = threadIdx.x;
    int grp = t >> 4;          // 0..15
    int q = t & 15;
    int n = blockIdx.x * 16 + grp;
    if (n >= N) return;
    unsigned beg = off[n], end = off[n + 1];
    float4 acc = make_float4(0.f, 0.f, 0.f, 0.f);
    for (unsigned base2 = beg; base2 < end; base2 += 16) {
        unsigned idx = base2 + q;
        int pd = (idx < end) ? pay[idx] : 0;
        int jmax = (int)min(16u, end - base2);
        int j = 0;
        for (; j + 8 <= jmax; j += 8) {
            int s0 = __shfl(pd, j + 0, 16);
            int s1 = __shfl(pd, j + 1, 16);
            int s2 = __shfl(pd, j + 2, 16);
            int s3 = __shfl(pd, j + 3, 16);
            int s4 = __shfl(pd, j + 4, 16);
            int s5 = __shfl(pd, j + 5, 16);
            int s6 = __shfl(pd, j + 6, 16);
            int s7 = __shfl(pd, j + 7, 16);
            float4 a0 = bf4(*(const ushort4*)(h0b + (size_t)s0 * DOUT + 4 * q));
            float4 a1 = bf4(*(const ushort4*)(h0b + (size_t)s1 * DOUT + 4 * q));
            float4 a2 = bf4(*(const ushort4*)(h0b + (size_t)s2 * DOUT + 4 * q));
            float4 a3 = bf4(*(const ushort4*)(h0b + (size_t)s3 * DOUT + 4 * q));
            float4 a4 = bf4(*(const ushort4*)(h0b + (size_t)s4 * DOUT + 4 * q));
            float4 a5 = bf4(*(const ushort4*)(h0b + (size_t)s5 * DOUT + 4 * q));
            float4 a6 = bf4(*(const ushort4*)(h0b + (size_t)s6 * DOUT + 4 * q));
            float4 a7 = bf4(*(const ushort4*)(h0b + (size_t)s7 * DOUT + 4 * q));
            acc.x += ((a0.x + a1.x) + (a2.x + a3.x)) + ((a4.x + a5.x) + (a6.x + a7.x));
            acc.y += ((a0.y + a1.y) + (a2.y + a3.y)) + ((a4.y + a5.y) + (a6.y + a7.y));
            acc.z += ((a0.z + a1.z) + (a2.z + a3.z)) + ((a4.z + a5.z) + (a6.z + a7.z));
            acc.w += ((a0.w + a1.w) + (a2.w + a3.w)) + ((a4.w + a5.w) + (a6.w + a7.w));
        }
        for (; j + 4 <= jmax; j += 4) {
            int s0 = __shfl(pd, j + 0, 16);
            int s1 = __shfl(pd, j + 1, 16);
            int s2 = __shfl(pd, j + 2, 16);
            int s3 = __shfl(pd, j + 3, 16);
            float4 a0 = bf4(*(const ushort4*)(h0b + (size_t)s0 * DOUT + 4 * q));
            float4 a1 = bf4(*(const ushort4*)(h0b + (size_t)s1 * DOUT + 4 * q));
            float4 a2 = bf4(*(const ushort4*)(h0b + (size_t)s2 * DOUT + 4 * q));
            float4 a3 = bf4(*(const ushort4*)(h0b + (size_t)s3 * DOUT + 4 * q));
            acc.x += (a0.x + a1.x) + (a2.x + a3.x);
            acc.y += (a0.y + a1.y) + (a2.y + a3.y);
            acc.z += (a0.z + a1.z) + (a2.z + a3.z);
            acc.w += (a0.w + a1.w) + (a2.w + a3.w);
        }
        for (; j < jmax; ++j) {
            int s = __shfl(pd, j, 16);
            float4 a = bf4(*(const ushort4*)(h0b + (size_t)s * DOUT + 4 * q));
            acc.x += a.x; acc.y += a.y; acc.z += a.z; acc.w += a.w;
        }
    }
    float dv = dinv[n];
    float4 hs = *(const float4*)(h0s + (size_t)n * DOUT + 4 * q);
    float4 bv = *(const float4*)(b + 4 * q);
    float4 o;
    o.x = dv * (acc.x + hs.x) + bv.x;
    o.y = dv * (acc.y + hs.y) + bv.y;
    o.z = dv * (acc.z + hs.z) + bv.z;
    o.w = dv * (acc.w + hs.w) + bv.w;
    *(float4*)(h + (size_t)n * DOUT + 4 * q) = o;
    ushort4 ob;
    ob.x = f2bf(o.x); ob.y = f2bf(o.y); ob.z = f2bf(o.z); ob.w = f2bf(o.w);
    *(ushort4*)(hb + (size_t)n * DOUT + 4 * q) = ob;
}

// ---------- K9: gather energy + S(bf16) — neighbor rows from bf16 mirror ----------
// R13: S stored bf16. S enters out only as w*2c_n*S with c_n~1e-4 ->
// bf16 error contributes ~2e-7 to out, four orders below absmax.
__global__ __launch_bounds__(256) void k_energy(const unsigned* __restrict__ off,
                                                const int* __restrict__ pay,
                                                const float* __restrict__ h,
                                                const unsigned short* __restrict__ hb,
                                                float* __restrict__ e,
                                                unsigned short* __restrict__ Sb, int N) {
    int t = threadIdx.x;
    int grp = t >> 4;
    int q = t & 15;
    int n = blockIdx.x * 16 + grp;
    if (n >= N) return;
    unsigned beg = off[n], end = off[n + 1];
    float4 hm = *(const float4*)(h + (size_t)n * DOUT + 4 * q);
    float4 Sa = make_float4(0.f, 0.f, 0.f, 0.f);
    float esum = 0.f;
#define EACC(a)                                                                \
    {                                                                          \
        Sa.x += a.x; Sa.y += a.y; Sa.z += a.z; Sa.w += a.w;                    \
        float dx = hm.x - a.x, dy = hm.y - a.y, dz = hm.z - a.z, dw = hm.w - a.w; \
        esum += dx * dx + dy * dy + dz * dz + dw * dw;                         \
    }
    for (unsigned base2 = beg; base2 < end; base2 += 16) {
        unsigned idx = base2 + q;
        int pd = (idx < end) ? pay[idx] : 0;
        int jmax = (int)min(16u, end - base2);
        int j = 0;
        for (; j + 8 <= jmax; j += 8) {
            int s0 = __shfl(pd, j + 0, 16);
            int s1 = __shfl(pd, j + 1, 16);
            int s2 = __shfl(pd, j + 2, 16);
            int s3 = __shfl(pd, j + 3, 16);
            int s4 = __shfl(pd, j + 4, 16);
            int s5 = __shfl(pd, j + 5, 16);
            int s6 = __shfl(pd, j + 6, 16);
            int s7 = __shfl(pd, j + 7, 16);
            float4 a0 = bf4(*(const ushort4*)(hb + (size_t)s0 * DOUT + 4 * q));
            float4 a1 = bf4(*(const ushort4*)(hb + (size_t)s1 * DOUT + 4 * q));
            float4 a2 = bf4(*(const ushort4*)(hb + (size_t)s2 * DOUT + 4 * q));
            float4 a3 = bf4(*(const ushort4*)(hb + (size_t)s3 * DOUT + 4 * q));
            float4 a4 = bf4(*(const ushort4*)(hb + (size_t)s4 * DOUT + 4 * q));
            float4 a5 = bf4(*(const ushort4*)(hb + (size_t)s5 * DOUT + 4 * q));
            float4 a6 = bf4(*(const ushort4*)(hb + (size_t)s6 * DOUT + 4 * q));
            float4 a7 = bf4(*(const ushort4*)(hb + (size_t)s7 * DOUT + 4 * q));
            EACC(a0) EACC(a1) EACC(a2) EACC(a3) EACC(a4) EACC(a5) EACC(a6) EACC(a7)
        }
        for (; j + 4 <= jmax; j += 4) {
            int s0 = __shfl(pd, j + 0, 16);
            int s1 = __shfl(pd, j + 1, 16);
            int s2 = __shfl(pd, j + 2, 16);
            int s3 = __shfl(pd, j + 3, 16);
            float4 a0 = bf4(*(const ushort4*)(hb + (size_t)s0 * DOUT + 4 * q));
            float4 a1 = bf4(*(const ushort4*)(hb + (size_t)s1 * DOUT + 4 * q));
            float4 a2 = bf4(*(const ushort4*)(hb + (size_t)s2 * DOUT + 4 * q));
            float4 a3 = bf4(*(const ushort4*)(hb + (size_t)s3 * DOUT + 4 * q));
            EACC(a0) EACC(a1) EACC(a2) EACC(a3)
        }
        for (; j < jmax; ++j) {
            int s = __shfl(pd, j, 16);
            float4 a = bf4(*(const ushort4*)(hb + (size_t)s * DOUT + 4 * q));
            EACC(a)
        }
    }
#undef EACC
#pragma unroll
    for (int m = 1; m <= 8; m <<= 1) esum += __shfl_xor(esum, m, 16);
    if (q == 0) e[n] = esum;
    ushort4 sb;
    sb.x = f2bf(Sa.x); sb.y = f2bf(Sa.y); sb.z = f2bf(Sa.z); sb.w = f2bf(Sa.w);
    *(ushort4*)(Sb + (size_t)n * DOUT + 4 * q) = sb;
}

// ---------- K10: per-block softmax partials (m, Z, M) ----------
__global__ __launch_bounds__(256) void k_stats1(const float* __restrict__ e,
                                                const float* __restrict__ Tptr,
                                                float* __restrict__ part, int N) {
    float T = *Tptr;
    float m = -3.4e38f;
    int i0 = blockIdx.x * 256 + threadIdx.x;
    int stride = gridDim.x * 256;
    for (int i = i0; i < N; i += stride) m = fmaxf(m, -e[i] / T);
    __shared__ float sm[256];
    sm[threadIdx.x] = m;
    __syncthreads();
    for (int s = 128; s > 0; s >>= 1) {
        if (threadIdx.x < s) sm[threadIdx.x] = fmaxf(sm[threadIdx.x], sm[threadIdx.x + s]);
        __syncthreads();
    }
    float bm = sm[0];
    __syncthreads();
    float z = 0.f, mm = 0.f;
    for (int i = i0; i < N; i += stride) {
        float t = -e[i] / T - bm;
        float w = __expf(t);
        z += w;
        mm += w * t;
    }
    __shared__ float sz[256], sM[256];
    sz[threadIdx.x] = z;
    sM[threadIdx.x] = mm;
    __syncthreads();
    for (int s = 128; s > 0; s >>= 1) {
        if (threadIdx.x < s) {
            sz[threadIdx.x] += sz[threadIdx.x + s];
            sM[threadIdx.x] += sM[threadIdx.x + s];
        }
        __syncthreads();
    }
    if (threadIdx.x == 0) {
        part[blockIdx.x * 3 + 0] = bm;
        part[blockIdx.x * 3 + 1] = sz[0];
        part[blockIdx.x * 3 + 2] = sM[0];
    }
}

// ---------- K11: merge partials -> st = {m, Z, M} ----------
__global__ __launch_bounds__(256) void k_stats2(const float* __restrict__ part,
                                                float* __restrict__ st, int P) {
    __shared__ float sm[256];
    float m = -3.4e38f;
    for (int i = threadIdx.x; i < P; i += 256) m = fmaxf(m, part[3 * i]);
    sm[threadIdx.x] = m;
    __syncthreads();
    for (int s = 128; s > 0; s >>= 1) {
        if (threadIdx.x < s) sm[threadIdx.x] = fmaxf(sm[threadIdx.x], sm[threadIdx.x + s]);
        __syncthreads();
    }
    float gm = sm[0];
    __syncthreads();
    float Z = 0.f, M = 0.f;
    for (int i = threadIdx.x; i < P; i += 256) {
        float mb = part[3 * i], zb = part[3 * i + 1], Mb = part[3 * i + 2];
        float d = mb - gm, eb = __expf(d);
        Z += eb * zb;
        M += eb * (Mb + d * zb);
    }
    __shared__ float sz[256], sM2[256];
    sz[threadIdx.x] = Z;
    sM2[threadIdx.x] = M;
    __syncthreads();
    for (int s = 128; s > 0; s >>= 1) {
        if (threadIdx.x < s) {
            sz[threadIdx.x] += sz[threadIdx.x + s];
            sM2[threadIdx.x] += sM2[threadIdx.x + s];
        }
        __syncthreads();
    }
    if (threadIdx.x == 0) {
        st[0] = gm;
        st[1] = sz[0];
        st[2] = sM2[0];
    }
}

// ---------- K12: c_n = p_n * (logp_n + H) ----------
__global__ __launch_bounds__(256) void k_coef(const float* __restrict__ e,
                                              const float* __restrict__ Tptr,
                                              const float* __restrict__ st,
                                              float* __restrict__ c, int N) {
    int n = blockIdx.x * 256 + threadIdx.x;
    if (n >= N) return;
    float T = *Tptr;
    float gm = st[0], Z = st[1], M = st[2];
    float logZ = logf(Z);
    float H = logZ - M / Z;
    float t = -e[n] / T - gm;
    float lp = t - logZ;
    c[n] = expf(lp) * (lp + H);
}

// ---------- K13: out-CSR gather of A,B + fused final — hb gather, Sb bf16 ----------
__global__ __launch_bounds__(256) void k_grad_final(const unsigned* __restrict__ off,
                                                    const int* __restrict__ pay,
                                                    const float* __restrict__ c,
                                                    const float* __restrict__ h,
                                                    const unsigned short* __restrict__ hb,
                                                    const unsigned short* __restrict__ Sb,
                                                    const unsigned* __restrict__ cnt,
                                                    const float* __restrict__ wptr,
                                                    float* __restrict__ out, int N) {
    int t = threadIdx.x;
    int grp = t >> 4;
    int q = t & 15;
    int n = blockIdx.x * 16 + grp;
    if (n >= N) return;
    unsigned beg = off[n], end = off[n + 1];
    float A = 0.f;
    float4 B = make_float4(0.f, 0.f, 0.f, 0.f);
    for (unsigned base2 = beg; base2 < end; base2 += 16) {
        unsigned idx = base2 + q;
        int pd = 0;
        float cv = 0.f;
        if (idx < end) {
            pd = pay[idx];
            cv = c[pd];
        }
        int jmax = (int)min(16u, end - base2);
        int j = 0;
        for (; j + 8 <= jmax; j += 8) {
            int s0 = __shfl(pd, j + 0, 16);
            int s1 = __shfl(pd, j + 1, 16);
            int s2 = __shfl(pd, j + 2, 16);
            int s3 = __shfl(pd, j + 3, 16);
            int s4 = __shfl(pd, j + 4, 16);
            int s5 = __shfl(pd, j + 5, 16);
            int s6 = __shfl(pd, j + 6, 16);
            int s7 = __shfl(pd, j + 7, 16);
            float c0 = __shfl(cv, j + 0, 16);
            float c1 = __shfl(cv, j + 1, 16);
            float c2 = __shfl(cv, j + 2, 16);
            float c3 = __shfl(cv, j + 3, 16);
            float c4 = __shfl(cv, j + 4, 16);
            float c5 = __shfl(cv, j + 5, 16);
            float c6 = __shfl(cv, j + 6, 16);
            float c7 = __shfl(cv, j + 7, 16);
            float4 a0 = bf4(*(const ushort4*)(hb + (size_t)s0 * DOUT + 4 * q));
            float4 a1 = bf4(*(const ushort4*)(hb + (size_t)s1 * DOUT + 4 * q));
            float4 a2 = bf4(*(const ushort4*)(hb + (size_t)s2 * DOUT + 4 * q));
            float4 a3 = bf4(*(const ushort4*)(hb + (size_t)s3 * DOUT + 4 * q));
            float4 a4 = bf4(*(const ushort4*)(hb + (size_t)s4 * DOUT + 4 * q));
            float4 a5 = bf4(*(const ushort4*)(hb + (size_t)s5 * DOUT + 4 * q));
            float4 a6 = bf4(*(const ushort4*)(hb + (size_t)s6 * DOUT + 4 * q));
            float4 a7 = bf4(*(const ushort4*)(hb + (size_t)s7 * DOUT + 4 * q));
            A += ((c0 + c1) + (c2 + c3)) + ((c4 + c5) + (c6 + c7));
            B.x = fmaf(c0, a0.x, fmaf(c1, a1.x, fmaf(c2, a2.x, fmaf(c3, a3.x, B.x))));
            B.x = fmaf(c4, a4.x, fmaf(c5, a5.x, fmaf(c6, a6.x, fmaf(c7, a7.x, B.x))));
            B.y = fmaf(c0, a0.y, fmaf(c1, a1.y, fmaf(c2, a2.y, fmaf(c3, a3.y, B.y))));
            B.y = fmaf(c4, a4.y, fmaf(c5, a5.y, fmaf(c6, a6.y, fmaf(c7, a7.y, B.y))));
            B.z = fmaf(c0, a0.z, fmaf(c1, a1.z, fmaf(c2, a2.z, fmaf(c3, a3.z, B.z))));
            B.z = fmaf(c4, a4.z, fmaf(c5, a5.z, fmaf(c6, a6.z, fmaf(c7, a7.z, B.z))));
            B.w = fmaf(c0, a0.w, fmaf(c1, a1.w, fmaf(c2, a2.w, fmaf(c3, a3.w, B.w))));
            B.w = fmaf(c4, a4.w, fmaf(c5, a5.w, fmaf(c6, a6.w, fmaf(c7, a7.w, B.w))));
        }
        for (; j + 4 <= jmax; j += 4) {
            int s0 = __shfl(pd, j + 0, 16);
            int s1 = __shfl(pd, j + 1, 16);
            int s2 = __shfl(pd, j + 2, 16);
            int s3 = __shfl(pd, j + 3, 16);
            float c0 = __shfl(cv, j + 0, 16);
            float c1 = __shfl(cv, j + 1, 16);
            float c2 = __shfl(cv, j + 2, 16);
            float c3 = __shfl(cv, j + 3, 16);
            float4 a0 = bf4(*(const ushort4*)(hb + (size_t)s0 * DOUT + 4 * q));
            float4 a1 = bf4(*(const ushort4*)(hb + (size_t)s1 * DOUT + 4 * q));
            float4 a2 = bf4(*(const ushort4*)(hb + (size_t)s2 * DOUT + 4 * q));
            float4 a3 = bf4(*(const ushort4*)(hb + (size_t)s3 * DOUT + 4 * q));
            A += (c0 + c1) + (c2 + c3);
            B.x = fmaf(c0, a0.x, fmaf(c1, a1.x, fmaf(c2, a2.x, fmaf(c3, a3.x, B.x))));
            B.y = fmaf(c0, a0.y, fmaf(c1, a1.y, fmaf(c2, a2.y, fmaf(c3, a3.y, B.y))));
            B.z = fmaf(c0, a0.z, fmaf(c1, a1.z, fmaf(c2, a2.z, fmaf(c3, a3.z, B.z))));
            B.w = fmaf(c0, a0.w, fmaf(c1, a1.w, fmaf(c2, a2.w, fmaf(c3, a3.w, B.w))));
        }
        for (; j < jmax; ++j) {
            int s = __shfl(pd, j, 16);
            float cj = __shfl(cv, j, 16);
            float4 a = bf4(*(const ushort4*)(hb + (size_t)s * DOUT + 4 * q));
            A += cj;
            B.x = fmaf(cj, a.x, B.x);
            B.y = fmaf(cj, a.y, B.y);
            B.z = fmaf(cj, a.z, B.z);
            B.w = fmaf(cj, a.w, B.w);
        }
    }
    size_t idx4 = (size_t)n * DOUT + 4 * q;
    float4 hm = *(const float4*)(h + idx4);
    float4 Sv = bf4(*(const ushort4*)(Sb + idx4));
    float cn = c[n];
    float cc = (float)cnt[n];
    float w = *wptr;
    float4 o;
    o.x = hm.x + w * (2.f * cn * (cc * hm.x - Sv.x) + 2.f * (A * hm.x - B.x));
    o.y = hm.y + w * (2.f * cn * (cc * hm.y - Sv.y) + 2.f * (A * hm.y - B.y));
    o.z = hm.z + w * (2.f * cn * (cc * hm.z - Sv.z) + 2.f * (A * hm.z - B.z));
    o.w = hm.w + w * (2.f * cn * (cc * hm.w - Sv.w) + 2.f * (A * hm.w - B.w));
    *(float4*)(out + idx4) = o;
}

extern "C" void kernel_launch(void* const* d_in, const int* in_sizes, int n_in,
                              void* d_out, int out_size, void* d_ws, size_t ws_size,
                              hipStream_t stream) {
    const float* x    = (const float*)d_in[0];
    const int*   ei   = (const int*)d_in[1];
    const float* wptr = (const float*)d_in[2];
    const float* Tptr = (const float*)d_in[3];
    const float* W    = (const float*)d_in[4];
    const float* b    = (const float*)d_in[5];
    float* out = (float*)d_out;

    const int N  = in_sizes[0] / DIN;   // 100000
    const int E  = in_sizes[1] / 2;     // 1000000
    const int NE = N * DOUT;
    const int* src = ei;
    const int* dst = ei + E;

    const int NBUK = (N + BW - 1) / BW;         // 196
    const int NC   = (E + EPC - 1) / EPC;       // 245
    const int M    = NBUK * NC;
    const int M2   = 2 * M;
    const int NBs  = (M2 + 255) / 256;          // <= 1024

    // workspace layout
    float*    h0s  = (float*)d_ws;                    // NE (bf16 S reuses this later)
    float*    h    = h0s + NE;                        // NE
    int2*     bkt  = (int2*)(h + NE);                 // E int2 (8 MB, reused per dir)
    int*      pay1 = (int*)(bkt + E);                 // E (in-CSR payload: src ids)
    int*      pay2 = pay1 + E;                        // E (out-CSR payload: dst ids)
    unsigned* counts = (unsigned*)(pay2 + E);         // 2*M
    unsigned* bsum = counts + M2;                     // <=1024
    unsigned* off1 = bsum + 1024;                     // N+1
    unsigned* off2 = off1 + N + 1;                    // N+1
    unsigned* cnt  = off2 + N + 1;                    // N
    float*    e    = (float*)(cnt + N);               // N
    float*    c    = e + N;                           // N
    float*    dinv = c + N;                           // N
    float*    part = dinv + N;                        // 3*NSTATB
    float*    st   = part + 3 * NSTATB;               // 3

    // W fragment buffers (16B-aligned), then bf16 mirrors of h and h0s
    uintptr_t fb = (uintptr_t)(st + 3);
    fb = (fb + 15) & ~(uintptr_t)15;
    short8v* whf = (short8v*)fb;                      // [16][64] short8
    short8v* wlf = whf + 16 * 64;
    unsigned short* hb  = (unsigned short*)(wlf + 16 * 64);  // NE bf16 (12.8 MB)
    unsigned short* h0b = hb + NE;                           // NE bf16 (12.8 MB)
    unsigned short* Sb  = (unsigned short*)h0s;              // NE bf16, reuse h0s after k_agg

    const int nodeG = (N + 15) / 16;    // 16 nodes per 256-thread block
    const int nodeBlocks = (N + 255) / 256;

    // W fragment pack (independent of everything else)
    k_prepw<<<1, 256, 0, stream>>>(W, whf, wlf);

    // build both direction counts + one combined scan
    k_countboth<<<NC, 256, 0, stream>>>(src, dst, counts, NBUK, NC, E);
    k_scanA<<<NBs, 256, 0, stream>>>(counts, bsum, M2);
    k_scan2<<<1, 1024, 0, stream>>>(bsum, NBs);
    k_scanC<<<NBs, 256, 0, stream>>>(counts, bsum, M2);

    // direction 0: in-CSR (key=dst, payload=src) -> off1/pay1 + cnt/dinv
    k_bucket<<<NC, 256, 0, stream>>>(dst, src, counts, 0, 0u, bkt, NBUK, NC, E);
    k_csr<<<NBUK, 256, 0, stream>>>(bkt, counts, off1, pay1, cnt, dinv,
                                    0, 0u, NBUK, NC, N, E);
    // direction 1: out-CSR (key=src, payload=dst) -> off2/pay2
    k_bucket<<<NC, 256, 0, stream>>>(src, dst, counts, M, (unsigned)E, bkt, NBUK, NC, E);
    k_csr<<<NBUK, 256, 0, stream>>>(bkt, counts, off2, pay2, nullptr, nullptr,
                                    M, (unsigned)E, NBUK, NC, N, E);

    k_gemm<<<(N + 63) / 64, 256, 0, stream>>>(x, whf, wlf, dinv, h0s, h0b, N);
    k_agg<<<nodeG, 256, 0, stream>>>(off1, pay1, dinv, h0s, h0b, b, h, hb, N);
    k_energy<<<nodeG, 256, 0, stream>>>(off1, pay1, h, hb, e, Sb, N);
    k_stats1<<<NSTATB, 256, 0, stream>>>(e, Tptr, part, N);
    k_stats2<<<1, 256, 0, stream>>>(part, st, NSTATB);
    k_coef<<<nodeBlocks, 256, 0, stream>>>(e, Tptr, st, c, N);
    k_grad_final<<<nodeG, 256, 0, stream>>>(off2, pay2, c, h, hb, Sb, cnt, wptr, out, N);
}